// Round 1
// baseline (6465.646 us; speedup 1.0000x reference)
//
#include <hip/hip_runtime.h>
#include <hip/hip_bf16.h>
#include <math.h>

#define NNODES 100000
#define NEDGES 1600000
#define NBATCH 2048
#define FDIM   128
#define BN_EPS 1e-5f

// ---------------------------------------------------------------------------
// init: deg = 1 (self loop), zero the stats accumulators
// ---------------------------------------------------------------------------
__global__ void k_init(unsigned* __restrict__ deg, float* __restrict__ stats, int nstats) {
    int i = blockIdx.x * 256 + threadIdx.x;
    if (i < NNODES) deg[i] = 1u;
    if (i < nstats) stats[i] = 0.f;
}

__global__ void k_deg(const int* __restrict__ dst, unsigned* __restrict__ deg) {
    int e = blockIdx.x * 256 + threadIdx.x;
    if (e < NEDGES) atomicAdd(&deg[dst[e]], 1u);
}

__global__ void k_dinv(const unsigned* __restrict__ deg, float* __restrict__ dinv) {
    int i = blockIdx.x * 256 + threadIdx.x;
    if (i < NNODES) dinv[i] = rsqrtf((float)deg[i]);
}

// ---------------------------------------------------------------------------
// GCN layer-1 GEMM: H = X @ W ; A = H * dinv[row]  (accumulator w/ self-loop)
// block = 128 threads (one per output feature), R rows per block
// ---------------------------------------------------------------------------
template<int K, int R>
__global__ void k_gcn_gemm1(const float* __restrict__ X, const float* __restrict__ W,
                            const float* __restrict__ dinv,
                            float* __restrict__ Hout, float* __restrict__ Aout) {
    __shared__ float xs[R][K];
    int f = threadIdx.x;
    int row0 = blockIdx.x * R;
    for (int t = threadIdx.x; t < R * K; t += 128) {
        int r = t / K, k = t - r * K;
        int rr = row0 + r;
        xs[r][k] = (rr < NNODES) ? X[rr * K + k] : 0.f;
    }
    __syncthreads();
    float acc[R];
#pragma unroll
    for (int r = 0; r < R; ++r) acc[r] = 0.f;
    for (int k = 0; k < K; ++k) {
        float w = W[k * FDIM + f];
#pragma unroll
        for (int r = 0; r < R; ++r) acc[r] = fmaf(xs[r][k], w, acc[r]);
    }
#pragma unroll
    for (int r = 0; r < R; ++r) {
        int rr = row0 + r;
        if (rr < NNODES) {
            float v = acc[r];
            Hout[rr * FDIM + f] = v;
            Aout[rr * FDIM + f] = v * dinv[rr];
        }
    }
}

// ---------------------------------------------------------------------------
// GCN layer-2 GEMM with BN folded into the input load.
// In-place: Aout may alias X (each block reads only its own rows into LDS
// before writing them) -> no __restrict__ on those.
// ---------------------------------------------------------------------------
template<int R>
__global__ void k_gcn_gemm2(const float* X, const float* __restrict__ aS,
                            const float* __restrict__ bS, const float* __restrict__ W,
                            const float* __restrict__ dinv,
                            float* __restrict__ Hout, float* Aout) {
    __shared__ float xs[R][FDIM];
    int f = threadIdx.x;
    int row0 = blockIdx.x * R;
    for (int t = threadIdx.x; t < R * FDIM; t += 128) {
        int r = t >> 7, k = t & 127;
        int rr = row0 + r;
        xs[r][k] = (rr < NNODES) ? fmaf(X[rr * FDIM + k], aS[k], bS[k]) : 0.f;
    }
    __syncthreads();
    float acc[R];
#pragma unroll
    for (int r = 0; r < R; ++r) acc[r] = 0.f;
    for (int k = 0; k < FDIM; ++k) {
        float w = W[k * FDIM + f];
#pragma unroll
        for (int r = 0; r < R; ++r) acc[r] = fmaf(xs[r][k], w, acc[r]);
    }
#pragma unroll
    for (int r = 0; r < R; ++r) {
        int rr = row0 + r;
        if (rr < NNODES) {
            float v = acc[r];
            Hout[rr * FDIM + f] = v;
            Aout[rr * FDIM + f] = v * dinv[rr];
        }
    }
}

// ---------------------------------------------------------------------------
// Edge aggregation: acc[dst] += dinv[src] * H[src]
// thread t -> edge e = t/32, feature group fg = (t%32)*4 (float4)
// ---------------------------------------------------------------------------
__global__ void k_edges(const int* __restrict__ src, const int* __restrict__ dst,
                        const float* __restrict__ dinv, const float* __restrict__ Hs,
                        float* __restrict__ acc) {
    int t = blockIdx.x * 256 + threadIdx.x;
    int e = t >> 5;
    if (e >= NEDGES) return;
    int fg = (t & 31) << 2;
    int s = src[e], d = dst[e];
    float ds = dinv[s];
    const float4 h4 = *(const float4*)(Hs + (size_t)s * FDIM + fg);
    float* ap = acc + (size_t)d * FDIM + fg;
    unsafeAtomicAdd(ap + 0, h4.x * ds);
    unsafeAtomicAdd(ap + 1, h4.y * ds);
    unsafeAtomicAdd(ap + 2, h4.z * ds);
    unsafeAtomicAdd(ap + 3, h4.w * ds);
}

// ---------------------------------------------------------------------------
// GCN finalize: X = relu(acc*dinv + bias), accumulate per-feature sum/sumsq
// ---------------------------------------------------------------------------
template<int R>
__global__ void k_finalize(const float* __restrict__ Acc, const float* __restrict__ dinv,
                           const float* __restrict__ bias, float* __restrict__ Xout,
                           float* __restrict__ sum, float* __restrict__ sumsq) {
    int f = threadIdx.x;
    int row0 = blockIdx.x * R;
    float bf = bias[f];
    float s = 0.f, s2 = 0.f;
#pragma unroll
    for (int r = 0; r < R; ++r) {
        int rr = row0 + r;
        if (rr < NNODES) {
            float v = fmaf(Acc[rr * FDIM + f], dinv[rr], bf);
            v = fmaxf(v, 0.f);
            Xout[rr * FDIM + f] = v;
            s += v;
            s2 = fmaf(v, v, s2);
        }
    }
    unsafeAtomicAdd(&sum[f], s);
    unsafeAtomicAdd(&sumsq[f], s2);
}

// ---------------------------------------------------------------------------
// BN params: a = gamma*rsqrt(var+eps), b = beta - mu*a   (one block, 128 thr)
// ---------------------------------------------------------------------------
__global__ void k_bnparams(const float* __restrict__ sum, const float* __restrict__ sumsq,
                           const float* __restrict__ gamma, const float* __restrict__ beta,
                           float* __restrict__ aOut, float* __restrict__ bOut, float invN) {
    int f = threadIdx.x;
    float mu = sum[f] * invN;
    float var = sumsq[f] * invN - mu * mu;
    float a = gamma[f] * rsqrtf(var + BN_EPS);
    aOut[f] = a;
    bOut[f] = beta[f] - mu * a;
}

// ---------------------------------------------------------------------------
// Segment max with BN applied per element. ibatch is sorted; block g binary
// searches its row range. Deterministic, no atomics.
// ---------------------------------------------------------------------------
__global__ void k_segmax(const float* __restrict__ X, const int* __restrict__ ibatch,
                         const float* __restrict__ aS, const float* __restrict__ bS,
                         float* __restrict__ out) {
    int g = blockIdx.x;
    int f = threadIdx.x;
    __shared__ int bounds[2];
    if (threadIdx.x < 2) {
        int target = g + (int)threadIdx.x;
        int lo = 0, hi = NNODES;
        while (lo < hi) {
            int mid = (lo + hi) >> 1;
            if (ibatch[mid] < target) lo = mid + 1; else hi = mid;
        }
        bounds[threadIdx.x] = lo;
    }
    __syncthreads();
    float af = aS[f], bf = bS[f];
    float m = -INFINITY;
    for (int r = bounds[0]; r < bounds[1]; ++r)
        m = fmaxf(m, fmaf(X[(size_t)r * FDIM + f], af, bf));
    out[g * FDIM + f] = m;
}

// ---------------------------------------------------------------------------
// Branch layer 1: Y = tanh(X @ W + bias) + per-feature stats
// ---------------------------------------------------------------------------
template<int K, int R>
__global__ void k_branch_l1(const float* __restrict__ X, const float* __restrict__ W,
                            const float* __restrict__ bias, float* __restrict__ Y,
                            float* __restrict__ sum, float* __restrict__ sumsq) {
    __shared__ float xs[R][K];
    int f = threadIdx.x;
    int row0 = blockIdx.x * R;
    for (int t = threadIdx.x; t < R * K; t += 128) {
        int r = t / K, k = t - r * K;
        int rr = row0 + r;
        xs[r][k] = (rr < NBATCH) ? X[(size_t)rr * K + k] : 0.f;
    }
    __syncthreads();
    float acc[R];
#pragma unroll
    for (int r = 0; r < R; ++r) acc[r] = 0.f;
    for (int k = 0; k < K; ++k) {
        float w = W[k * FDIM + f];
#pragma unroll
        for (int r = 0; r < R; ++r) acc[r] = fmaf(xs[r][k], w, acc[r]);
    }
    float bf = bias[f];
    float s = 0.f, s2 = 0.f;
#pragma unroll
    for (int r = 0; r < R; ++r) {
        int rr = row0 + r;
        if (rr < NBATCH) {
            float v = tanhf(acc[r] + bf);
            Y[rr * FDIM + f] = v;
            s += v;
            s2 = fmaf(v, v, s2);
        }
    }
    unsafeAtomicAdd(&sum[f], s);
    unsafeAtomicAdd(&sumsq[f], s2);
}

// ---------------------------------------------------------------------------
// Branch layer 2: out = relu((Y*a+b) @ W + bias)
// ---------------------------------------------------------------------------
template<int R>
__global__ void k_branch_l2(const float* __restrict__ Y, const float* __restrict__ aS,
                            const float* __restrict__ bS, const float* __restrict__ W,
                            const float* __restrict__ bias, float* __restrict__ out) {
    __shared__ float xs[R][FDIM];
    int f = threadIdx.x;
    int row0 = blockIdx.x * R;
    for (int t = threadIdx.x; t < R * FDIM; t += 128) {
        int r = t >> 7, k = t & 127;
        int rr = row0 + r;
        xs[r][k] = (rr < NBATCH) ? fmaf(Y[rr * FDIM + k], aS[k], bS[k]) : 0.f;
    }
    __syncthreads();
    float acc[R];
#pragma unroll
    for (int r = 0; r < R; ++r) acc[r] = 0.f;
    for (int k = 0; k < FDIM; ++k) {
        float w = W[k * FDIM + f];
#pragma unroll
        for (int r = 0; r < R; ++r) acc[r] = fmaf(xs[r][k], w, acc[r]);
    }
#pragma unroll
    for (int r = 0; r < R; ++r) {
        int rr = row0 + r;
        if (rr < NBATCH) out[rr * FDIM + f] = fmaxf(acc[r] + bias[f], 0.f);
    }
}

// ---------------------------------------------------------------------------
extern "C" void kernel_launch(void* const* d_in, const int* in_sizes, int n_in,
                              void* d_out, int out_size, void* d_ws, size_t ws_size,
                              hipStream_t stream) {
    const float* Xs    = (const float*)d_in[0];
    const int*   adj   = (const int*)d_in[1];
    const int*   esrc  = adj;
    const int*   edst  = adj + NEDGES;
    const int*   ibat  = (const int*)d_in[2];
    const float* Xchem = (const float*)d_in[3];
    const float* Xtgt  = (const float*)d_in[4];
    const float* Xcell = (const float*)d_in[5];
    const float* Wc1 = (const float*)d_in[6],  *bc1 = (const float*)d_in[7];
    const float* g1  = (const float*)d_in[8],  *be1 = (const float*)d_in[9];
    const float* Wc2 = (const float*)d_in[10], *bc2 = (const float*)d_in[11];
    const float* g2  = (const float*)d_in[12], *be2 = (const float*)d_in[13];
    const float* Wh1 = (const float*)d_in[14], *bh1 = (const float*)d_in[15];
    const float* gh  = (const float*)d_in[16], *beh = (const float*)d_in[17];
    const float* Wh2 = (const float*)d_in[18], *bh2 = (const float*)d_in[19];
    const float* Wt1 = (const float*)d_in[20], *bt1 = (const float*)d_in[21];
    const float* gt  = (const float*)d_in[22], *bet = (const float*)d_in[23];
    const float* Wt2 = (const float*)d_in[24], *bt2 = (const float*)d_in[25];
    const float* Wg1 = (const float*)d_in[26], *bg1 = (const float*)d_in[27];
    const float* gg  = (const float*)d_in[28], *beg = (const float*)d_in[29];
    const float* Wg2 = (const float*)d_in[30], *bg2 = (const float*)d_in[31];

    // workspace layout
    float*    buf0 = (float*)d_ws;                         // N*128
    float*    buf1 = buf0 + (size_t)NNODES * FDIM;         // N*128
    unsigned* deg  = (unsigned*)(buf1 + (size_t)NNODES * FDIM); // N u32
    float*    dinv = (float*)(deg + NNODES);               // N f32
    float*    stats = dinv + NNODES;                       // 5 * 256
    float*    bnab  = stats + 5 * 256;                     // 5 * 256
    float*    ybuf  = bnab + 5 * 256;                      // 2048*128

    float* sum_g1 = stats + 0 * 256, *ssq_g1 = sum_g1 + 128;
    float* sum_g2 = stats + 1 * 256, *ssq_g2 = sum_g2 + 128;
    float* sum_ch = stats + 2 * 256, *ssq_ch = sum_ch + 128;
    float* sum_tg = stats + 3 * 256, *ssq_tg = sum_tg + 128;
    float* sum_cl = stats + 4 * 256, *ssq_cl = sum_cl + 128;
    float* a_g1 = bnab + 0 * 256, *b_g1 = a_g1 + 128;
    float* a_g2 = bnab + 1 * 256, *b_g2 = a_g2 + 128;
    float* a_ch = bnab + 2 * 256, *b_ch = a_ch + 128;
    float* a_tg = bnab + 3 * 256, *b_tg = a_tg + 128;
    float* a_cl = bnab + 4 * 256, *b_cl = a_cl + 128;

    float* out_stru = (float*)d_out;
    float* out_chem = out_stru + (size_t)NBATCH * FDIM;
    float* out_tgt  = out_chem + (size_t)NBATCH * FDIM;
    float* out_cell = out_tgt + (size_t)NBATCH * FDIM;

    const float invN = 1.f / (float)NNODES;
    const float invB = 1.f / (float)NBATCH;

    // --- degree + norm ---
    k_init<<<(NNODES + 255) / 256, 256, 0, stream>>>(deg, stats, 5 * 256);
    k_deg<<<(NEDGES + 255) / 256, 256, 0, stream>>>(edst, deg);
    k_dinv<<<(NNODES + 255) / 256, 256, 0, stream>>>(deg, dinv);

    // --- GCN layer 1 ---
    k_gcn_gemm1<78, 16><<<(NNODES + 15) / 16, 128, 0, stream>>>(Xs, Wc1, dinv, buf0, buf1);
    k_edges<<<(NEDGES * 32) / 256, 256, 0, stream>>>(esrc, edst, dinv, buf0, buf1);
    k_finalize<16><<<(NNODES + 15) / 16, 128, 0, stream>>>(buf1, dinv, bc1, buf0, sum_g1, ssq_g1);
    k_bnparams<<<1, 128, 0, stream>>>(sum_g1, ssq_g1, g1, be1, a_g1, b_g1, invN);

    // --- GCN layer 2 (BN of layer 1 folded into the load) ---
    k_gcn_gemm2<16><<<(NNODES + 15) / 16, 128, 0, stream>>>(buf0, a_g1, b_g1, Wc2, dinv, buf1, buf0);
    k_edges<<<(NEDGES * 32) / 256, 256, 0, stream>>>(esrc, edst, dinv, buf1, buf0);
    k_finalize<16><<<(NNODES + 15) / 16, 128, 0, stream>>>(buf0, dinv, bc2, buf1, sum_g2, ssq_g2);
    k_bnparams<<<1, 128, 0, stream>>>(sum_g2, ssq_g2, g2, be2, a_g2, b_g2, invN);

    // --- segment max (BN2 applied per element) ---
    k_segmax<<<NBATCH, 128, 0, stream>>>(buf1, ibat, a_g2, b_g2, out_stru);

    // --- chem branch (K=256) ---
    k_branch_l1<256, 16><<<NBATCH / 16, 128, 0, stream>>>(Xchem, Wh1, bh1, ybuf, sum_ch, ssq_ch);
    k_bnparams<<<1, 128, 0, stream>>>(sum_ch, ssq_ch, gh, beh, a_ch, b_ch, invB);
    k_branch_l2<16><<<NBATCH / 16, 128, 0, stream>>>(ybuf, a_ch, b_ch, Wh2, bh2, out_chem);

    // --- target branch (K=2048) ---
    k_branch_l1<2048, 4><<<NBATCH / 4, 128, 0, stream>>>(Xtgt, Wt1, bt1, ybuf, sum_tg, ssq_tg);
    k_bnparams<<<1, 128, 0, stream>>>(sum_tg, ssq_tg, gt, bet, a_tg, b_tg, invB);
    k_branch_l2<16><<<NBATCH / 16, 128, 0, stream>>>(ybuf, a_tg, b_tg, Wt2, bt2, out_tgt);

    // --- cell branch (K=1024) ---
    k_branch_l1<1024, 8><<<NBATCH / 8, 128, 0, stream>>>(Xcell, Wg1, bg1, ybuf, sum_cl, ssq_cl);
    k_bnparams<<<1, 128, 0, stream>>>(sum_cl, ssq_cl, gg, beg, a_cl, b_cl, invB);
    k_branch_l2<16><<<NBATCH / 16, 128, 0, stream>>>(ybuf, a_cl, b_cl, Wg2, bg2, out_cell);
}

// Round 2
// 1987.376 us; speedup vs baseline: 3.2534x; 3.2534x over previous
//
#include <hip/hip_runtime.h>
#include <hip/hip_bf16.h>
#include <math.h>

#define NNODES 100000
#define NEDGES 1600000
#define NBATCH 2048
#define FDIM   128
#define BN_EPS 1e-5f

#define SCAN_T 1024                                  // total scan threads
#define CHUNK  ((NNODES + SCAN_T - 1) / SCAN_T)      // 98 elements/thread

// ---------------------------------------------------------------------------
// init: deg = 1 (self loop), zero the stats accumulators
// ---------------------------------------------------------------------------
__global__ void k_init(unsigned* __restrict__ deg, float* __restrict__ stats, int nstats) {
    int i = blockIdx.x * 256 + threadIdx.x;
    if (i < NNODES) deg[i] = 1u;
    if (i < nstats) stats[i] = 0.f;
}

__global__ void k_deg(const int* __restrict__ dst, unsigned* __restrict__ deg) {
    int e = blockIdx.x * 256 + threadIdx.x;
    if (e < NEDGES) atomicAdd(&deg[dst[e]], 1u);
}

__global__ void k_dinv(const unsigned* __restrict__ deg, float* __restrict__ dinv) {
    int i = blockIdx.x * 256 + threadIdx.x;
    if (i < NNODES) dinv[i] = rsqrtf((float)deg[i]);
}

// ---------------------------------------------------------------------------
// CSR build: 2-level exclusive scan of in-degree counts (deg-1), then
// counting-sort scatter of src indices.
// ---------------------------------------------------------------------------
__global__ void k_scan1(const unsigned* __restrict__ deg, unsigned* __restrict__ tsum) {
    int i = blockIdx.x * 256 + threadIdx.x;      // 0..SCAN_T-1
    int lo = i * CHUNK, hi = min(lo + CHUNK, NNODES);
    unsigned s = 0;
    for (int e = lo; e < hi; ++e) s += deg[e] - 1u;
    tsum[i] = s;
}

__global__ void k_scan2(const unsigned* __restrict__ tsum, unsigned* __restrict__ toff) {
    __shared__ unsigned sh[SCAN_T];
    int t = threadIdx.x;
    sh[t] = tsum[t];
    __syncthreads();
    for (int off = 1; off < SCAN_T; off <<= 1) {
        unsigned v = (t >= off) ? sh[t - off] : 0u;
        __syncthreads();
        sh[t] += v;
        __syncthreads();
    }
    toff[t] = (t == 0) ? 0u : sh[t - 1];          // exclusive
}

__global__ void k_scan3(const unsigned* __restrict__ deg, const unsigned* __restrict__ toff,
                        int* __restrict__ rowStart, int* __restrict__ cursor) {
    int i = blockIdx.x * 256 + threadIdx.x;
    int lo = i * CHUNK, hi = min(lo + CHUNK, NNODES);
    unsigned run = toff[i];
    for (int e = lo; e < hi; ++e) {
        rowStart[e] = (int)run;
        cursor[e]   = (int)run;
        run += deg[e] - 1u;
    }
    if (i == SCAN_T - 1) rowStart[NNODES] = NEDGES;
}

__global__ void k_scatter(const int* __restrict__ src, const int* __restrict__ dst,
                          int* __restrict__ cursor, int* __restrict__ csr_src) {
    int e = blockIdx.x * 256 + threadIdx.x;
    if (e < NEDGES) {
        int d = dst[e];
        int pos = atomicAdd(&cursor[d], 1);
        csr_src[pos] = src[e];
    }
}

// ---------------------------------------------------------------------------
// GCN layer-1 GEMM: H = X @ W     (K=78)
// ---------------------------------------------------------------------------
template<int K, int R>
__global__ void k_gcn_gemm1(const float* __restrict__ X, const float* __restrict__ W,
                            float* __restrict__ Hout) {
    __shared__ float xs[R][K];
    int f = threadIdx.x;
    int row0 = blockIdx.x * R;
    for (int t = threadIdx.x; t < R * K; t += 128) {
        int r = t / K, k = t - r * K;
        int rr = row0 + r;
        xs[r][k] = (rr < NNODES) ? X[rr * K + k] : 0.f;
    }
    __syncthreads();
    float acc[R];
#pragma unroll
    for (int r = 0; r < R; ++r) acc[r] = 0.f;
    for (int k = 0; k < K; ++k) {
        float w = W[k * FDIM + f];
#pragma unroll
        for (int r = 0; r < R; ++r) acc[r] = fmaf(xs[r][k], w, acc[r]);
    }
#pragma unroll
    for (int r = 0; r < R; ++r) {
        int rr = row0 + r;
        if (rr < NNODES) Hout[rr * FDIM + f] = acc[r];
    }
}

// ---------------------------------------------------------------------------
// GCN layer-2 GEMM with BN folded into the input load: H = (X*a+b) @ W
// ---------------------------------------------------------------------------
template<int R>
__global__ void k_gcn_gemm2(const float* __restrict__ X, const float* __restrict__ aS,
                            const float* __restrict__ bS, const float* __restrict__ W,
                            float* __restrict__ Hout) {
    __shared__ float xs[R][FDIM];
    int f = threadIdx.x;
    int row0 = blockIdx.x * R;
    for (int t = threadIdx.x; t < R * FDIM; t += 128) {
        int r = t >> 7, k = t & 127;
        int rr = row0 + r;
        xs[r][k] = (rr < NNODES) ? fmaf(X[rr * FDIM + k], aS[k], bS[k]) : 0.f;
    }
    __syncthreads();
    float acc[R];
#pragma unroll
    for (int r = 0; r < R; ++r) acc[r] = 0.f;
    for (int k = 0; k < FDIM; ++k) {
        float w = W[k * FDIM + f];
#pragma unroll
        for (int r = 0; r < R; ++r) acc[r] = fmaf(xs[r][k], w, acc[r]);
    }
#pragma unroll
    for (int r = 0; r < R; ++r) {
        int rr = row0 + r;
        if (rr < NNODES) Hout[rr * FDIM + f] = acc[r];
    }
}

// ---------------------------------------------------------------------------
// CSR gather + finalize (fused): for each node d,
//   acc = H[d]*dinv[d] + sum_{in-edges} dinv[s]*H[s]
//   X   = relu(acc*dinv[d] + bias);   accumulate per-feature sum/sumsq
// One 128-thread block handles G nodes sequentially; thread = feature.
// ---------------------------------------------------------------------------
template<int G>
__global__ void k_gather_fin(const float* __restrict__ H, const int* __restrict__ rowStart,
                             const int* __restrict__ csr_src, const float* __restrict__ dinv,
                             const float* __restrict__ bias, float* __restrict__ Xout,
                             float* __restrict__ sum, float* __restrict__ sumsq) {
    int f = threadIdx.x;
    int n0 = blockIdx.x * G;
    float bf = bias[f];
    float s = 0.f, s2 = 0.f;
#pragma unroll
    for (int g = 0; g < G; ++g) {
        int d = n0 + g;
        if (d >= NNODES) break;
        float dd = dinv[d];
        float acc = H[(size_t)d * FDIM + f] * dd;          // self-loop term
        int lo = rowStart[d], hi = rowStart[d + 1];
        for (int j = lo; j < hi; ++j) {
            int sN = csr_src[j];
            acc = fmaf(dinv[sN], H[(size_t)sN * FDIM + f], acc);
        }
        float v = fmaxf(fmaf(acc, dd, bf), 0.f);
        Xout[(size_t)d * FDIM + f] = v;
        s += v;
        s2 = fmaf(v, v, s2);
    }
    unsafeAtomicAdd(&sum[f], s);
    unsafeAtomicAdd(&sumsq[f], s2);
}

// ---------------------------------------------------------------------------
// BN params: a = gamma*rsqrt(var+eps), b = beta - mu*a
// ---------------------------------------------------------------------------
__global__ void k_bnparams(const float* __restrict__ sum, const float* __restrict__ sumsq,
                           const float* __restrict__ gamma, const float* __restrict__ beta,
                           float* __restrict__ aOut, float* __restrict__ bOut, float invN) {
    int f = threadIdx.x;
    float mu = sum[f] * invN;
    float var = sumsq[f] * invN - mu * mu;
    float a = gamma[f] * rsqrtf(var + BN_EPS);
    aOut[f] = a;
    bOut[f] = beta[f] - mu * a;
}

// ---------------------------------------------------------------------------
// Segment max with BN applied per element (ibatch sorted; binary search range)
// ---------------------------------------------------------------------------
__global__ void k_segmax(const float* __restrict__ X, const int* __restrict__ ibatch,
                         const float* __restrict__ aS, const float* __restrict__ bS,
                         float* __restrict__ out) {
    int g = blockIdx.x;
    int f = threadIdx.x;
    __shared__ int bounds[2];
    if (threadIdx.x < 2) {
        int target = g + (int)threadIdx.x;
        int lo = 0, hi = NNODES;
        while (lo < hi) {
            int mid = (lo + hi) >> 1;
            if (ibatch[mid] < target) lo = mid + 1; else hi = mid;
        }
        bounds[threadIdx.x] = lo;
    }
    __syncthreads();
    float af = aS[f], bf = bS[f];
    float m = -INFINITY;
    for (int r = bounds[0]; r < bounds[1]; ++r)
        m = fmaxf(m, fmaf(X[(size_t)r * FDIM + f], af, bf));
    out[g * FDIM + f] = m;
}

// ---------------------------------------------------------------------------
// Branch layer 1: Y = tanh(X @ W + bias) + per-feature stats
// ---------------------------------------------------------------------------
template<int K, int R>
__global__ void k_branch_l1(const float* __restrict__ X, const float* __restrict__ W,
                            const float* __restrict__ bias, float* __restrict__ Y,
                            float* __restrict__ sum, float* __restrict__ sumsq) {
    __shared__ float xs[R][K];
    int f = threadIdx.x;
    int row0 = blockIdx.x * R;
    for (int t = threadIdx.x; t < R * K; t += 128) {
        int r = t / K, k = t - r * K;
        int rr = row0 + r;
        xs[r][k] = (rr < NBATCH) ? X[(size_t)rr * K + k] : 0.f;
    }
    __syncthreads();
    float acc[R];
#pragma unroll
    for (int r = 0; r < R; ++r) acc[r] = 0.f;
    for (int k = 0; k < K; ++k) {
        float w = W[k * FDIM + f];
#pragma unroll
        for (int r = 0; r < R; ++r) acc[r] = fmaf(xs[r][k], w, acc[r]);
    }
    float bf = bias[f];
    float s = 0.f, s2 = 0.f;
#pragma unroll
    for (int r = 0; r < R; ++r) {
        int rr = row0 + r;
        if (rr < NBATCH) {
            float v = tanhf(acc[r] + bf);
            Y[(size_t)rr * FDIM + f] = v;
            s += v;
            s2 = fmaf(v, v, s2);
        }
    }
    unsafeAtomicAdd(&sum[f], s);
    unsafeAtomicAdd(&sumsq[f], s2);
}

// ---------------------------------------------------------------------------
// Branch layer 2: out = relu((Y*a+b) @ W + bias)
// ---------------------------------------------------------------------------
template<int R>
__global__ void k_branch_l2(const float* __restrict__ Y, const float* __restrict__ aS,
                            const float* __restrict__ bS, const float* __restrict__ W,
                            const float* __restrict__ bias, float* __restrict__ out) {
    __shared__ float xs[R][FDIM];
    int f = threadIdx.x;
    int row0 = blockIdx.x * R;
    for (int t = threadIdx.x; t < R * FDIM; t += 128) {
        int r = t >> 7, k = t & 127;
        int rr = row0 + r;
        xs[r][k] = (rr < NBATCH) ? fmaf(Y[(size_t)rr * FDIM + k], aS[k], bS[k]) : 0.f;
    }
    __syncthreads();
    float acc[R];
#pragma unroll
    for (int r = 0; r < R; ++r) acc[r] = 0.f;
    for (int k = 0; k < FDIM; ++k) {
        float w = W[k * FDIM + f];
#pragma unroll
        for (int r = 0; r < R; ++r) acc[r] = fmaf(xs[r][k], w, acc[r]);
    }
#pragma unroll
    for (int r = 0; r < R; ++r) {
        int rr = row0 + r;
        if (rr < NBATCH) out[(size_t)rr * FDIM + f] = fmaxf(acc[r] + bias[f], 0.f);
    }
}

// ---------------------------------------------------------------------------
extern "C" void kernel_launch(void* const* d_in, const int* in_sizes, int n_in,
                              void* d_out, int out_size, void* d_ws, size_t ws_size,
                              hipStream_t stream) {
    const float* Xs    = (const float*)d_in[0];
    const int*   adj   = (const int*)d_in[1];
    const int*   esrc  = adj;
    const int*   edst  = adj + NEDGES;
    const int*   ibat  = (const int*)d_in[2];
    const float* Xchem = (const float*)d_in[3];
    const float* Xtgt  = (const float*)d_in[4];
    const float* Xcell = (const float*)d_in[5];
    const float* Wc1 = (const float*)d_in[6],  *bc1 = (const float*)d_in[7];
    const float* g1  = (const float*)d_in[8],  *be1 = (const float*)d_in[9];
    const float* Wc2 = (const float*)d_in[10], *bc2 = (const float*)d_in[11];
    const float* g2  = (const float*)d_in[12], *be2 = (const float*)d_in[13];
    const float* Wh1 = (const float*)d_in[14], *bh1 = (const float*)d_in[15];
    const float* gh  = (const float*)d_in[16], *beh = (const float*)d_in[17];
    const float* Wh2 = (const float*)d_in[18], *bh2 = (const float*)d_in[19];
    const float* Wt1 = (const float*)d_in[20], *bt1 = (const float*)d_in[21];
    const float* gt  = (const float*)d_in[22], *bet = (const float*)d_in[23];
    const float* Wt2 = (const float*)d_in[24], *bt2 = (const float*)d_in[25];
    const float* Wg1 = (const float*)d_in[26], *bg1 = (const float*)d_in[27];
    const float* gg  = (const float*)d_in[28], *beg = (const float*)d_in[29];
    const float* Wg2 = (const float*)d_in[30], *bg2 = (const float*)d_in[31];

    // workspace layout
    float*    buf0 = (float*)d_ws;                              // N*128
    float*    buf1 = buf0 + (size_t)NNODES * FDIM;              // N*128
    unsigned* deg  = (unsigned*)(buf1 + (size_t)NNODES * FDIM); // N u32
    float*    dinv = (float*)(deg + NNODES);                    // N f32
    int*      rowStart = (int*)(dinv + NNODES);                 // N+1
    int*      cursor   = rowStart + NNODES + 1;                 // N
    unsigned* tsum = (unsigned*)(cursor + NNODES);              // SCAN_T
    unsigned* toff = tsum + SCAN_T;                             // SCAN_T
    int*      csr_src = (int*)(toff + SCAN_T);                  // E
    float*    stats = (float*)(csr_src + NEDGES);               // 5 * 256
    float*    bnab  = stats + 5 * 256;                          // 5 * 256
    float*    ybuf  = bnab + 5 * 256;                           // 2048*128

    float* sum_g1 = stats + 0 * 256, *ssq_g1 = sum_g1 + 128;
    float* sum_g2 = stats + 1 * 256, *ssq_g2 = sum_g2 + 128;
    float* sum_ch = stats + 2 * 256, *ssq_ch = sum_ch + 128;
    float* sum_tg = stats + 3 * 256, *ssq_tg = sum_tg + 128;
    float* sum_cl = stats + 4 * 256, *ssq_cl = sum_cl + 128;
    float* a_g1 = bnab + 0 * 256, *b_g1 = a_g1 + 128;
    float* a_g2 = bnab + 1 * 256, *b_g2 = a_g2 + 128;
    float* a_ch = bnab + 2 * 256, *b_ch = a_ch + 128;
    float* a_tg = bnab + 3 * 256, *b_tg = a_tg + 128;
    float* a_cl = bnab + 4 * 256, *b_cl = a_cl + 128;

    float* out_stru = (float*)d_out;
    float* out_chem = out_stru + (size_t)NBATCH * FDIM;
    float* out_tgt  = out_chem + (size_t)NBATCH * FDIM;
    float* out_cell = out_tgt + (size_t)NBATCH * FDIM;

    const float invN = 1.f / (float)NNODES;
    const float invB = 1.f / (float)NBATCH;

    // --- degree + norm + CSR build ---
    k_init<<<(NNODES + 255) / 256, 256, 0, stream>>>(deg, stats, 5 * 256);
    k_deg<<<(NEDGES + 255) / 256, 256, 0, stream>>>(edst, deg);
    k_dinv<<<(NNODES + 255) / 256, 256, 0, stream>>>(deg, dinv);
    k_scan1<<<SCAN_T / 256, 256, 0, stream>>>(deg, tsum);
    k_scan2<<<1, SCAN_T, 0, stream>>>(tsum, toff);
    k_scan3<<<SCAN_T / 256, 256, 0, stream>>>(deg, toff, rowStart, cursor);
    k_scatter<<<(NEDGES + 255) / 256, 256, 0, stream>>>(esrc, edst, cursor, csr_src);

    // --- GCN layer 1 ---
    k_gcn_gemm1<78, 16><<<(NNODES + 15) / 16, 128, 0, stream>>>(Xs, Wc1, buf0);
    k_gather_fin<8><<<(NNODES + 7) / 8, 128, 0, stream>>>(buf0, rowStart, csr_src, dinv,
                                                          bc1, buf1, sum_g1, ssq_g1);
    k_bnparams<<<1, 128, 0, stream>>>(sum_g1, ssq_g1, g1, be1, a_g1, b_g1, invN);

    // --- GCN layer 2 (BN of layer 1 folded into the load) ---
    k_gcn_gemm2<16><<<(NNODES + 15) / 16, 128, 0, stream>>>(buf1, a_g1, b_g1, Wc2, buf0);
    k_gather_fin<8><<<(NNODES + 7) / 8, 128, 0, stream>>>(buf0, rowStart, csr_src, dinv,
                                                          bc2, buf1, sum_g2, ssq_g2);
    k_bnparams<<<1, 128, 0, stream>>>(sum_g2, ssq_g2, g2, be2, a_g2, b_g2, invN);

    // --- segment max (BN2 applied per element) ---
    k_segmax<<<NBATCH, 128, 0, stream>>>(buf1, ibat, a_g2, b_g2, out_stru);

    // --- chem branch (K=256) ---
    k_branch_l1<256, 16><<<NBATCH / 16, 128, 0, stream>>>(Xchem, Wh1, bh1, ybuf, sum_ch, ssq_ch);
    k_bnparams<<<1, 128, 0, stream>>>(sum_ch, ssq_ch, gh, beh, a_ch, b_ch, invB);
    k_branch_l2<16><<<NBATCH / 16, 128, 0, stream>>>(ybuf, a_ch, b_ch, Wh2, bh2, out_chem);

    // --- target branch (K=2048) ---
    k_branch_l1<2048, 4><<<NBATCH / 4, 128, 0, stream>>>(Xtgt, Wt1, bt1, ybuf, sum_tg, ssq_tg);
    k_bnparams<<<1, 128, 0, stream>>>(sum_tg, ssq_tg, gt, bet, a_tg, b_tg, invB);
    k_branch_l2<16><<<NBATCH / 16, 128, 0, stream>>>(ybuf, a_tg, b_tg, Wt2, bt2, out_tgt);

    // --- cell branch (K=1024) ---
    k_branch_l1<1024, 8><<<NBATCH / 8, 128, 0, stream>>>(Xcell, Wg1, bg1, ybuf, sum_cl, ssq_cl);
    k_bnparams<<<1, 128, 0, stream>>>(sum_cl, ssq_cl, gg, beg, a_cl, b_cl, invB);
    k_branch_l2<16><<<NBATCH / 16, 128, 0, stream>>>(ybuf, a_cl, b_cl, Wg2, bg2, out_cell);
}

// Round 3
// 1335.925 us; speedup vs baseline: 4.8398x; 1.4876x over previous
//
#include <hip/hip_runtime.h>
#include <hip/hip_bf16.h>
#include <math.h>

#define NNODES 100000
#define NEDGES 1600000
#define NBATCH 2048
#define FDIM   128
#define BN_EPS 1e-5f

#define SCAN_T 1024                                  // total scan threads
#define CHUNK  ((NNODES + SCAN_T - 1) / SCAN_T)      // 98 elements/thread

#define GB_BLOCKS  3125                              // gather blocks
#define GB_BATCHES 12500                             // 8 nodes per batch

// ---------------------------------------------------------------------------
// init: deg = 1 (self loop), zero the stats accumulators
// ---------------------------------------------------------------------------
__global__ void k_init(unsigned* __restrict__ deg, float* __restrict__ stats, int nstats) {
    int i = blockIdx.x * 256 + threadIdx.x;
    if (i < NNODES) deg[i] = 1u;
    if (i < nstats) stats[i] = 0.f;
}

__global__ void k_deg(const int* __restrict__ dst, unsigned* __restrict__ deg) {
    int e = blockIdx.x * 256 + threadIdx.x;
    if (e < NEDGES) atomicAdd(&deg[dst[e]], 1u);
}

__global__ void k_dinv(const unsigned* __restrict__ deg, float* __restrict__ dinv) {
    int i = blockIdx.x * 256 + threadIdx.x;
    if (i < NNODES) dinv[i] = rsqrtf((float)deg[i]);
}

// ---------------------------------------------------------------------------
// CSR build: 2-level exclusive scan of in-degree counts (deg-1), then
// counting-sort scatter of src indices.
// ---------------------------------------------------------------------------
__global__ void k_scan1(const unsigned* __restrict__ deg, unsigned* __restrict__ tsum) {
    int i = blockIdx.x * 256 + threadIdx.x;      // 0..SCAN_T-1
    int lo = i * CHUNK, hi = min(lo + CHUNK, NNODES);
    unsigned s = 0;
    for (int e = lo; e < hi; ++e) s += deg[e] - 1u;
    tsum[i] = s;
}

__global__ void k_scan2(const unsigned* __restrict__ tsum, unsigned* __restrict__ toff) {
    __shared__ unsigned sh[SCAN_T];
    int t = threadIdx.x;
    sh[t] = tsum[t];
    __syncthreads();
    for (int off = 1; off < SCAN_T; off <<= 1) {
        unsigned v = (t >= off) ? sh[t - off] : 0u;
        __syncthreads();
        sh[t] += v;
        __syncthreads();
    }
    toff[t] = (t == 0) ? 0u : sh[t - 1];          // exclusive
}

__global__ void k_scan3(const unsigned* __restrict__ deg, const unsigned* __restrict__ toff,
                        int* __restrict__ rowStart, int* __restrict__ cursor) {
    int i = blockIdx.x * 256 + threadIdx.x;
    int lo = i * CHUNK, hi = min(lo + CHUNK, NNODES);
    unsigned run = toff[i];
    for (int e = lo; e < hi; ++e) {
        rowStart[e] = (int)run;
        cursor[e]   = (int)run;
        run += deg[e] - 1u;
    }
    if (i == SCAN_T - 1) rowStart[NNODES] = NEDGES;
}

__global__ void k_scatter(const int* __restrict__ src, const int* __restrict__ dst,
                          int* __restrict__ cursor, int* __restrict__ csr_src) {
    int e = blockIdx.x * 256 + threadIdx.x;
    if (e < NEDGES) {
        int d = dst[e];
        int pos = atomicAdd(&cursor[d], 1);
        csr_src[pos] = src[e];
    }
}

// ---------------------------------------------------------------------------
// GCN layer-1 GEMM: Hs = (X @ W) * dinv[row]     (K=78)
// ---------------------------------------------------------------------------
template<int K, int R>
__global__ void k_gcn_gemm1(const float* __restrict__ X, const float* __restrict__ W,
                            const float* __restrict__ dinv, float* __restrict__ Hout) {
    __shared__ float xs[R][K];
    int f = threadIdx.x;
    int row0 = blockIdx.x * R;
    for (int t = threadIdx.x; t < R * K; t += 128) {
        int r = t / K, k = t - r * K;
        int rr = row0 + r;
        xs[r][k] = (rr < NNODES) ? X[rr * K + k] : 0.f;
    }
    __syncthreads();
    float acc[R];
#pragma unroll
    for (int r = 0; r < R; ++r) acc[r] = 0.f;
    for (int k = 0; k < K; ++k) {
        float w = W[k * FDIM + f];
#pragma unroll
        for (int r = 0; r < R; ++r) acc[r] = fmaf(xs[r][k], w, acc[r]);
    }
#pragma unroll
    for (int r = 0; r < R; ++r) {
        int rr = row0 + r;
        if (rr < NNODES) Hout[(size_t)rr * FDIM + f] = acc[r] * dinv[rr];
    }
}

// ---------------------------------------------------------------------------
// GCN layer-2 GEMM, BN folded into the load: Hs = ((X*a+b) @ W) * dinv[row]
// ---------------------------------------------------------------------------
template<int R>
__global__ void k_gcn_gemm2(const float* __restrict__ X, const float* __restrict__ aS,
                            const float* __restrict__ bS, const float* __restrict__ W,
                            const float* __restrict__ dinv, float* __restrict__ Hout) {
    __shared__ float xs[R][FDIM];
    int f = threadIdx.x;
    int row0 = blockIdx.x * R;
    for (int t = threadIdx.x; t < R * FDIM; t += 128) {
        int r = t >> 7, k = t & 127;
        int rr = row0 + r;
        xs[r][k] = (rr < NNODES) ? fmaf(X[(size_t)rr * FDIM + k], aS[k], bS[k]) : 0.f;
    }
    __syncthreads();
    float acc[R];
#pragma unroll
    for (int r = 0; r < R; ++r) acc[r] = 0.f;
    for (int k = 0; k < FDIM; ++k) {
        float w = W[k * FDIM + f];
#pragma unroll
        for (int r = 0; r < R; ++r) acc[r] = fmaf(xs[r][k], w, acc[r]);
    }
#pragma unroll
    for (int r = 0; r < R; ++r) {
        int rr = row0 + r;
        if (rr < NNODES) Hout[(size_t)rr * FDIM + f] = acc[r] * dinv[rr];
    }
}

// ---------------------------------------------------------------------------
// CSR gather + finalize, MLP-optimized.
// Block = 256 threads = 8 node-slots x 32 lanes; lane owns a float4 feature
// group. Hs is pre-scaled by dinv[src], so per edge only ONE load (the row).
// Indices loaded 32-at-a-time (coalesced) and broadcast via shfl; row loads
// unrolled x4 -> ~8 independent loads in flight per wave.
//   out[d] = relu(dinv[d] * (Hs[d] + sum_nbr Hs[s]) + bias)
// BN stats reduced through LDS, one atomic per feature per block.
// ---------------------------------------------------------------------------
__global__ void k_gather_fin(const float* __restrict__ Hs, const int* __restrict__ rowStart,
                             const int* __restrict__ csr_src, const float* __restrict__ dinv,
                             const float* __restrict__ bias, float* __restrict__ Xout,
                             float* __restrict__ sum, float* __restrict__ sumsq) {
    __shared__ float redS[8][FDIM];
    __shared__ float redS2[8][FDIM];
    int tid = threadIdx.x;
    int ng  = tid >> 5;        // node slot 0..7
    int l32 = tid & 31;        // feature group (float4)

    const float4 b4 = *((const float4*)bias + l32);
    float4 stS  = {0.f, 0.f, 0.f, 0.f};
    float4 stS2 = {0.f, 0.f, 0.f, 0.f};

    for (int batch = blockIdx.x; batch < GB_BATCHES; batch += GB_BLOCKS) {
        int d = batch * 8 + ng;                       // 8*12500 == NNODES exactly
        float dd = dinv[d];
        float4 acc = *((const float4*)(Hs + (size_t)d * FDIM) + l32);  // self term
        int lo = rowStart[d], hi = rowStart[d + 1];
        for (int base = lo; base < hi; base += 32) {
            int cnt = hi - base; if (cnt > 32) cnt = 32;
            int idx = 0;
            if (base + l32 < hi) idx = csr_src[base + l32];   // coalesced 128B
            int j = 0;
            for (; j + 4 <= cnt; j += 4) {
                int s0 = __shfl(idx, j + 0, 32);
                int s1 = __shfl(idx, j + 1, 32);
                int s2 = __shfl(idx, j + 2, 32);
                int s3 = __shfl(idx, j + 3, 32);
                float4 h0 = *((const float4*)(Hs + (size_t)s0 * FDIM) + l32);
                float4 h1 = *((const float4*)(Hs + (size_t)s1 * FDIM) + l32);
                float4 h2 = *((const float4*)(Hs + (size_t)s2 * FDIM) + l32);
                float4 h3 = *((const float4*)(Hs + (size_t)s3 * FDIM) + l32);
                acc.x += h0.x + h1.x + h2.x + h3.x;
                acc.y += h0.y + h1.y + h2.y + h3.y;
                acc.z += h0.z + h1.z + h2.z + h3.z;
                acc.w += h0.w + h1.w + h2.w + h3.w;
            }
            for (; j < cnt; ++j) {
                int s0 = __shfl(idx, j, 32);
                float4 h0 = *((const float4*)(Hs + (size_t)s0 * FDIM) + l32);
                acc.x += h0.x; acc.y += h0.y; acc.z += h0.z; acc.w += h0.w;
            }
        }
        float4 v;
        v.x = fmaxf(fmaf(acc.x, dd, b4.x), 0.f);
        v.y = fmaxf(fmaf(acc.y, dd, b4.y), 0.f);
        v.z = fmaxf(fmaf(acc.z, dd, b4.z), 0.f);
        v.w = fmaxf(fmaf(acc.w, dd, b4.w), 0.f);
        *((float4*)(Xout + (size_t)d * FDIM) + l32) = v;
        stS.x += v.x; stS.y += v.y; stS.z += v.z; stS.w += v.w;
        stS2.x = fmaf(v.x, v.x, stS2.x);
        stS2.y = fmaf(v.y, v.y, stS2.y);
        stS2.z = fmaf(v.z, v.z, stS2.z);
        stS2.w = fmaf(v.w, v.w, stS2.w);
    }

    *((float4*)&redS[ng][l32 * 4])  = stS;
    *((float4*)&redS2[ng][l32 * 4]) = stS2;
    __syncthreads();
    if (tid < FDIM) {
        float a = 0.f;
#pragma unroll
        for (int g = 0; g < 8; ++g) a += redS[g][tid];
        unsafeAtomicAdd(&sum[tid], a);
    } else {
        int f = tid - FDIM;
        float a = 0.f;
#pragma unroll
        for (int g = 0; g < 8; ++g) a += redS2[g][f];
        unsafeAtomicAdd(&sumsq[f], a);
    }
}

// ---------------------------------------------------------------------------
// BN params: a = gamma*rsqrt(var+eps), b = beta - mu*a
// ---------------------------------------------------------------------------
__global__ void k_bnparams(const float* __restrict__ sum, const float* __restrict__ sumsq,
                           const float* __restrict__ gamma, const float* __restrict__ beta,
                           float* __restrict__ aOut, float* __restrict__ bOut, float invN) {
    int f = threadIdx.x;
    float mu = sum[f] * invN;
    float var = sumsq[f] * invN - mu * mu;
    float a = gamma[f] * rsqrtf(var + BN_EPS);
    aOut[f] = a;
    bOut[f] = beta[f] - mu * a;
}

// ---------------------------------------------------------------------------
// Segment max with BN applied per element (ibatch sorted; binary search range)
// ---------------------------------------------------------------------------
__global__ void k_segmax(const float* __restrict__ X, const int* __restrict__ ibatch,
                         const float* __restrict__ aS, const float* __restrict__ bS,
                         float* __restrict__ out) {
    int g = blockIdx.x;
    int f = threadIdx.x;
    __shared__ int bounds[2];
    if (threadIdx.x < 2) {
        int target = g + (int)threadIdx.x;
        int lo = 0, hi = NNODES;
        while (lo < hi) {
            int mid = (lo + hi) >> 1;
            if (ibatch[mid] < target) lo = mid + 1; else hi = mid;
        }
        bounds[threadIdx.x] = lo;
    }
    __syncthreads();
    float af = aS[f], bf = bS[f];
    float m = -INFINITY;
    for (int r = bounds[0]; r < bounds[1]; ++r)
        m = fmaxf(m, fmaf(X[(size_t)r * FDIM + f], af, bf));
    out[g * FDIM + f] = m;
}

// ---------------------------------------------------------------------------
// Branch layer 1: Y = tanh(X @ W + bias) + per-feature stats
// ---------------------------------------------------------------------------
template<int K, int R>
__global__ void k_branch_l1(const float* __restrict__ X, const float* __restrict__ W,
                            const float* __restrict__ bias, float* __restrict__ Y,
                            float* __restrict__ sum, float* __restrict__ sumsq) {
    __shared__ float xs[R][K];
    int f = threadIdx.x;
    int row0 = blockIdx.x * R;
    for (int t = threadIdx.x; t < R * K; t += 128) {
        int r = t / K, k = t - r * K;
        int rr = row0 + r;
        xs[r][k] = (rr < NBATCH) ? X[(size_t)rr * K + k] : 0.f;
    }
    __syncthreads();
    float acc[R];
#pragma unroll
    for (int r = 0; r < R; ++r) acc[r] = 0.f;
    for (int k = 0; k < K; ++k) {
        float w = W[k * FDIM + f];
#pragma unroll
        for (int r = 0; r < R; ++r) acc[r] = fmaf(xs[r][k], w, acc[r]);
    }
    float bf = bias[f];
    float s = 0.f, s2 = 0.f;
#pragma unroll
    for (int r = 0; r < R; ++r) {
        int rr = row0 + r;
        if (rr < NBATCH) {
            float v = tanhf(acc[r] + bf);
            Y[(size_t)rr * FDIM + f] = v;
            s += v;
            s2 = fmaf(v, v, s2);
        }
    }
    unsafeAtomicAdd(&sum[f], s);
    unsafeAtomicAdd(&sumsq[f], s2);
}

// ---------------------------------------------------------------------------
// Branch layer 2: out = relu((Y*a+b) @ W + bias)
// ---------------------------------------------------------------------------
template<int R>
__global__ void k_branch_l2(const float* __restrict__ Y, const float* __restrict__ aS,
                            const float* __restrict__ bS, const float* __restrict__ W,
                            const float* __restrict__ bias, float* __restrict__ out) {
    __shared__ float xs[R][FDIM];
    int f = threadIdx.x;
    int row0 = blockIdx.x * R;
    for (int t = threadIdx.x; t < R * FDIM; t += 128) {
        int r = t >> 7, k = t & 127;
        int rr = row0 + r;
        xs[r][k] = (rr < NBATCH) ? fmaf(Y[(size_t)rr * FDIM + k], aS[k], bS[k]) : 0.f;
    }
    __syncthreads();
    float acc[R];
#pragma unroll
    for (int r = 0; r < R; ++r) acc[r] = 0.f;
    for (int k = 0; k < FDIM; ++k) {
        float w = W[k * FDIM + f];
#pragma unroll
        for (int r = 0; r < R; ++r) acc[r] = fmaf(xs[r][k], w, acc[r]);
    }
#pragma unroll
    for (int r = 0; r < R; ++r) {
        int rr = row0 + r;
        if (rr < NBATCH) out[(size_t)rr * FDIM + f] = fmaxf(acc[r] + bias[f], 0.f);
    }
}

// ---------------------------------------------------------------------------
extern "C" void kernel_launch(void* const* d_in, const int* in_sizes, int n_in,
                              void* d_out, int out_size, void* d_ws, size_t ws_size,
                              hipStream_t stream) {
    const float* Xs    = (const float*)d_in[0];
    const int*   adj   = (const int*)d_in[1];
    const int*   esrc  = adj;
    const int*   edst  = adj + NEDGES;
    const int*   ibat  = (const int*)d_in[2];
    const float* Xchem = (const float*)d_in[3];
    const float* Xtgt  = (const float*)d_in[4];
    const float* Xcell = (const float*)d_in[5];
    const float* Wc1 = (const float*)d_in[6],  *bc1 = (const float*)d_in[7];
    const float* g1  = (const float*)d_in[8],  *be1 = (const float*)d_in[9];
    const float* Wc2 = (const float*)d_in[10], *bc2 = (const float*)d_in[11];
    const float* g2  = (const float*)d_in[12], *be2 = (const float*)d_in[13];
    const float* Wh1 = (const float*)d_in[14], *bh1 = (const float*)d_in[15];
    const float* gh  = (const float*)d_in[16], *beh = (const float*)d_in[17];
    const float* Wh2 = (const float*)d_in[18], *bh2 = (const float*)d_in[19];
    const float* Wt1 = (const float*)d_in[20], *bt1 = (const float*)d_in[21];
    const float* gt  = (const float*)d_in[22], *bet = (const float*)d_in[23];
    const float* Wt2 = (const float*)d_in[24], *bt2 = (const float*)d_in[25];
    const float* Wg1 = (const float*)d_in[26], *bg1 = (const float*)d_in[27];
    const float* gg  = (const float*)d_in[28], *beg = (const float*)d_in[29];
    const float* Wg2 = (const float*)d_in[30], *bg2 = (const float*)d_in[31];

    // workspace layout
    float*    buf0 = (float*)d_ws;                              // N*128
    float*    buf1 = buf0 + (size_t)NNODES * FDIM;              // N*128
    unsigned* deg  = (unsigned*)(buf1 + (size_t)NNODES * FDIM); // N u32
    float*    dinv = (float*)(deg + NNODES);                    // N f32
    int*      rowStart = (int*)(dinv + NNODES);                 // N+1
    int*      cursor   = rowStart + NNODES + 1;                 // N
    unsigned* tsum = (unsigned*)(cursor + NNODES);              // SCAN_T
    unsigned* toff = tsum + SCAN_T;                             // SCAN_T
    int*      csr_src = (int*)(toff + SCAN_T);                  // E
    float*    stats = (float*)(csr_src + NEDGES);               // 5 * 256
    float*    bnab  = stats + 5 * 256;                          // 5 * 256
    float*    ybuf  = bnab + 5 * 256;                           // 2048*128

    float* sum_g1 = stats + 0 * 256, *ssq_g1 = sum_g1 + 128;
    float* sum_g2 = stats + 1 * 256, *ssq_g2 = sum_g2 + 128;
    float* sum_ch = stats + 2 * 256, *ssq_ch = sum_ch + 128;
    float* sum_tg = stats + 3 * 256, *ssq_tg = sum_tg + 128;
    float* sum_cl = stats + 4 * 256, *ssq_cl = sum_cl + 128;
    float* a_g1 = bnab + 0 * 256, *b_g1 = a_g1 + 128;
    float* a_g2 = bnab + 1 * 256, *b_g2 = a_g2 + 128;
    float* a_ch = bnab + 2 * 256, *b_ch = a_ch + 128;
    float* a_tg = bnab + 3 * 256, *b_tg = a_tg + 128;
    float* a_cl = bnab + 4 * 256, *b_cl = a_cl + 128;

    float* out_stru = (float*)d_out;
    float* out_chem = out_stru + (size_t)NBATCH * FDIM;
    float* out_tgt  = out_chem + (size_t)NBATCH * FDIM;
    float* out_cell = out_tgt + (size_t)NBATCH * FDIM;

    const float invN = 1.f / (float)NNODES;
    const float invB = 1.f / (float)NBATCH;

    // --- degree + norm + CSR build ---
    k_init<<<(NNODES + 255) / 256, 256, 0, stream>>>(deg, stats, 5 * 256);
    k_deg<<<(NEDGES + 255) / 256, 256, 0, stream>>>(edst, deg);
    k_dinv<<<(NNODES + 255) / 256, 256, 0, stream>>>(deg, dinv);
    k_scan1<<<SCAN_T / 256, 256, 0, stream>>>(deg, tsum);
    k_scan2<<<1, SCAN_T, 0, stream>>>(tsum, toff);
    k_scan3<<<SCAN_T / 256, 256, 0, stream>>>(deg, toff, rowStart, cursor);
    k_scatter<<<(NEDGES + 255) / 256, 256, 0, stream>>>(esrc, edst, cursor, csr_src);

    // --- GCN layer 1 ---
    k_gcn_gemm1<78, 16><<<(NNODES + 15) / 16, 128, 0, stream>>>(Xs, Wc1, dinv, buf0);
    k_gather_fin<<<GB_BLOCKS, 256, 0, stream>>>(buf0, rowStart, csr_src, dinv,
                                                bc1, buf1, sum_g1, ssq_g1);
    k_bnparams<<<1, 128, 0, stream>>>(sum_g1, ssq_g1, g1, be1, a_g1, b_g1, invN);

    // --- GCN layer 2 (BN of layer 1 folded into the load) ---
    k_gcn_gemm2<16><<<(NNODES + 15) / 16, 128, 0, stream>>>(buf1, a_g1, b_g1, Wc2, dinv, buf0);
    k_gather_fin<<<GB_BLOCKS, 256, 0, stream>>>(buf0, rowStart, csr_src, dinv,
                                                bc2, buf1, sum_g2, ssq_g2);
    k_bnparams<<<1, 128, 0, stream>>>(sum_g2, ssq_g2, g2, be2, a_g2, b_g2, invN);

    // --- segment max (BN2 applied per element) ---
    k_segmax<<<NBATCH, 128, 0, stream>>>(buf1, ibat, a_g2, b_g2, out_stru);

    // --- chem branch (K=256) ---
    k_branch_l1<256, 16><<<NBATCH / 16, 128, 0, stream>>>(Xchem, Wh1, bh1, ybuf, sum_ch, ssq_ch);
    k_bnparams<<<1, 128, 0, stream>>>(sum_ch, ssq_ch, gh, beh, a_ch, b_ch, invB);
    k_branch_l2<16><<<NBATCH / 16, 128, 0, stream>>>(ybuf, a_ch, b_ch, Wh2, bh2, out_chem);

    // --- target branch (K=2048) ---
    k_branch_l1<2048, 4><<<NBATCH / 4, 128, 0, stream>>>(Xtgt, Wt1, bt1, ybuf, sum_tg, ssq_tg);
    k_bnparams<<<1, 128, 0, stream>>>(sum_tg, ssq_tg, gt, bet, a_tg, b_tg, invB);
    k_branch_l2<16><<<NBATCH / 16, 128, 0, stream>>>(ybuf, a_tg, b_tg, Wt2, bt2, out_tgt);

    // --- cell branch (K=1024) ---
    k_branch_l1<1024, 8><<<NBATCH / 8, 128, 0, stream>>>(Xcell, Wg1, bg1, ybuf, sum_cl, ssq_cl);
    k_bnparams<<<1, 128, 0, stream>>>(sum_cl, ssq_cl, gg, beg, a_cl, b_cl, invB);
    k_branch_l2<16><<<NBATCH / 16, 128, 0, stream>>>(ybuf, a_cl, b_cl, Wg2, bg2, out_cell);
}

// Round 4
// 1025.170 us; speedup vs baseline: 6.3069x; 1.3031x over previous
//
#include <hip/hip_runtime.h>
#include <hip/hip_bf16.h>
#include <math.h>

#define NNODES 100000
#define NEDGES 1600000
#define NBATCH 2048
#define FDIM   128
#define BN_EPS 1e-5f

#define SCAN_T 1024                                  // total scan threads
#define CHUNK  ((NNODES + SCAN_T - 1) / SCAN_T)      // 98 elements/thread

#define GB_BLOCKS  3125                              // gather blocks
#define GB_BATCHES 12500                             // 8 nodes per batch

// bf16 helpers (RNE)
__device__ __forceinline__ unsigned short f2bf(float x) {
    unsigned u = __float_as_uint(x);
    u += 0x7fff + ((u >> 16) & 1);
    return (unsigned short)(u >> 16);
}
__device__ __forceinline__ float bf2f(unsigned short s) {
    return __uint_as_float((unsigned)s << 16);
}

// ---------------------------------------------------------------------------
// init: deg = 1 (self loop), zero the stats accumulators
// ---------------------------------------------------------------------------
__global__ void k_init(unsigned* __restrict__ deg, float* __restrict__ stats, int nstats) {
    int i = blockIdx.x * 256 + threadIdx.x;
    if (i < NNODES) deg[i] = 1u;
    if (i < nstats) stats[i] = 0.f;
}

__global__ void k_deg(const int* __restrict__ dst, unsigned* __restrict__ deg) {
    int e = blockIdx.x * 256 + threadIdx.x;
    if (e < NEDGES) atomicAdd(&deg[dst[e]], 1u);
}

// ---------------------------------------------------------------------------
// CSR build: 2-level exclusive scan of in-degree counts (deg-1), then
// counting-sort scatter of src indices.  dinv computation fused into scan1.
// ---------------------------------------------------------------------------
__global__ void k_scan1(const unsigned* __restrict__ deg, unsigned* __restrict__ tsum,
                        float* __restrict__ dinv) {
    int i = blockIdx.x * 256 + threadIdx.x;      // 0..SCAN_T-1
    int lo = i * CHUNK, hi = min(lo + CHUNK, NNODES);
    unsigned s = 0;
    for (int e = lo; e < hi; ++e) {
        unsigned dg = deg[e];
        dinv[e] = rsqrtf((float)dg);
        s += dg - 1u;
    }
    tsum[i] = s;
}

__global__ void k_scan2(const unsigned* __restrict__ tsum, unsigned* __restrict__ toff) {
    __shared__ unsigned sh[SCAN_T];
    int t = threadIdx.x;
    sh[t] = tsum[t];
    __syncthreads();
    for (int off = 1; off < SCAN_T; off <<= 1) {
        unsigned v = (t >= off) ? sh[t - off] : 0u;
        __syncthreads();
        sh[t] += v;
        __syncthreads();
    }
    toff[t] = (t == 0) ? 0u : sh[t - 1];          // exclusive
}

__global__ void k_scan3(const unsigned* __restrict__ deg, const unsigned* __restrict__ toff,
                        int* __restrict__ rowStart, int* __restrict__ cursor) {
    int i = blockIdx.x * 256 + threadIdx.x;
    int lo = i * CHUNK, hi = min(lo + CHUNK, NNODES);
    unsigned run = toff[i];
    for (int e = lo; e < hi; ++e) {
        rowStart[e] = (int)run;
        cursor[e]   = (int)run;
        run += deg[e] - 1u;
    }
    if (i == SCAN_T - 1) rowStart[NNODES] = NEDGES;
}

__global__ void k_scatter(const int* __restrict__ src, const int* __restrict__ dst,
                          int* __restrict__ cursor, int* __restrict__ csr_src) {
    int e = blockIdx.x * 256 + threadIdx.x;
    if (e < NEDGES) {
        int d = dst[e];
        int pos = atomicAdd(&cursor[d], 1);
        csr_src[pos] = src[e];
    }
}

// ---------------------------------------------------------------------------
// GCN layer-1 GEMM: Hs = bf16( (X @ W) * dinv[row] )   (K=78)
// 6250 blocks x 16 rows == 100000 exactly (no bounds checks)
// ---------------------------------------------------------------------------
template<int K, int R>
__global__ __launch_bounds__(128) void k_gcn_gemm1(
        const float* __restrict__ X, const float* __restrict__ W,
        const float* __restrict__ dinv, unsigned short* __restrict__ Hout) {
    __shared__ float xs[R * K];
    int f = threadIdx.x;
    int row0 = blockIdx.x * R;
    for (int t = threadIdx.x; t < R * K; t += 128) {
        int r = t / K, k = t - r * K;
        xs[t] = X[(size_t)(row0 + r) * K + k];
    }
    __syncthreads();
    float acc[R];
#pragma unroll
    for (int r = 0; r < R; ++r) acc[r] = 0.f;
    for (int k = 0; k < K; ++k) {
        float w = W[k * FDIM + f];
#pragma unroll
        for (int r = 0; r < R; ++r) acc[r] = fmaf(xs[r * K + k], w, acc[r]);
    }
#pragma unroll
    for (int r = 0; r < R; ++r) {
        int rr = row0 + r;
        Hout[(size_t)rr * FDIM + f] = f2bf(acc[r] * dinv[rr]);
    }
}

// ---------------------------------------------------------------------------
// GCN layer-2 GEMM; BN(a,b) recomputed from stats in-prologue and folded into
// the load:  Hs = bf16( ((X*a+b) @ W) * dinv[row] )
// ---------------------------------------------------------------------------
template<int R>
__global__ __launch_bounds__(128) void k_gcn_gemm2(
        const float* __restrict__ X,
        const float* __restrict__ sum, const float* __restrict__ ssq,
        const float* __restrict__ gamma, const float* __restrict__ beta,
        const float* __restrict__ W, const float* __restrict__ dinv,
        unsigned short* __restrict__ Hout) {
    __shared__ float xs[R * FDIM];
    __shared__ float sa[FDIM], sb[FDIM];
    int f = threadIdx.x;
    {
        float mu  = sum[f] * (1.f / NNODES);
        float var = ssq[f] * (1.f / NNODES) - mu * mu;
        float a = gamma[f] * rsqrtf(var + BN_EPS);
        sa[f] = a;
        sb[f] = beta[f] - mu * a;
    }
    __syncthreads();
    int row0 = blockIdx.x * R;
    for (int t = threadIdx.x; t < R * FDIM; t += 128) {
        int r = t >> 7, k = t & 127;
        xs[t] = fmaf(X[(size_t)(row0 + r) * FDIM + k], sa[k], sb[k]);
    }
    __syncthreads();
    float acc[R];
#pragma unroll
    for (int r = 0; r < R; ++r) acc[r] = 0.f;
    for (int k = 0; k < FDIM; ++k) {
        float w = W[k * FDIM + f];
#pragma unroll
        for (int r = 0; r < R; ++r) acc[r] = fmaf(xs[r * FDIM + k], w, acc[r]);
    }
#pragma unroll
    for (int r = 0; r < R; ++r) {
        int rr = row0 + r;
        Hout[(size_t)rr * FDIM + f] = f2bf(acc[r] * dinv[rr]);
    }
}

// ---------------------------------------------------------------------------
// CSR gather + finalize over bf16 rows (256 B each).
// Block = 256 threads = 8 node-slots x 32 lanes; lane owns 4 bf16 features
// (ushort4, 8 B).  Indices loaded 32-at-a-time, broadcast via shfl; row loads
// unrolled x8 -> ~8+ independent loads in flight per wave.
//   out[d] = relu(dinv[d] * (Hs[d] + sum_nbr Hs[s]) + bias)   (fp32 accum)
// ---------------------------------------------------------------------------
__global__ __launch_bounds__(256) void k_gather_fin(
        const unsigned short* __restrict__ Hs, const int* __restrict__ rowStart,
        const int* __restrict__ csr_src, const float* __restrict__ dinv,
        const float* __restrict__ bias, float* __restrict__ Xout,
        float* __restrict__ sum, float* __restrict__ sumsq) {
    __shared__ float redS[8][FDIM];
    __shared__ float redS2[8][FDIM];
    int tid = threadIdx.x;
    int ng  = tid >> 5;        // node slot 0..7
    int l32 = tid & 31;        // feature group (4 features)

    const float4 b4 = *((const float4*)bias + l32);
    float4 stS  = {0.f, 0.f, 0.f, 0.f};
    float4 stS2 = {0.f, 0.f, 0.f, 0.f};

    for (int batch = blockIdx.x; batch < GB_BATCHES; batch += GB_BLOCKS) {
        int d = batch * 8 + ng;                       // 8*12500 == NNODES
        float dd = dinv[d];
        ushort4 hs = *((const ushort4*)(Hs + (size_t)d * FDIM) + l32);
        float4 acc = {bf2f(hs.x), bf2f(hs.y), bf2f(hs.z), bf2f(hs.w)};
        int lo = rowStart[d], hi = rowStart[d + 1];
        for (int base = lo; base < hi; base += 32) {
            int cnt = hi - base; if (cnt > 32) cnt = 32;
            int idx = 0;
            if (base + l32 < hi) idx = csr_src[base + l32];   // coalesced
            int j = 0;
            for (; j + 8 <= cnt; j += 8) {
                int s0 = __shfl(idx, j + 0, 32);
                int s1 = __shfl(idx, j + 1, 32);
                int s2 = __shfl(idx, j + 2, 32);
                int s3 = __shfl(idx, j + 3, 32);
                int s4 = __shfl(idx, j + 4, 32);
                int s5 = __shfl(idx, j + 5, 32);
                int s6 = __shfl(idx, j + 6, 32);
                int s7 = __shfl(idx, j + 7, 32);
                ushort4 h0 = *((const ushort4*)(Hs + (size_t)s0 * FDIM) + l32);
                ushort4 h1 = *((const ushort4*)(Hs + (size_t)s1 * FDIM) + l32);
                ushort4 h2 = *((const ushort4*)(Hs + (size_t)s2 * FDIM) + l32);
                ushort4 h3 = *((const ushort4*)(Hs + (size_t)s3 * FDIM) + l32);
                ushort4 h4 = *((const ushort4*)(Hs + (size_t)s4 * FDIM) + l32);
                ushort4 h5 = *((const ushort4*)(Hs + (size_t)s5 * FDIM) + l32);
                ushort4 h6 = *((const ushort4*)(Hs + (size_t)s6 * FDIM) + l32);
                ushort4 h7 = *((const ushort4*)(Hs + (size_t)s7 * FDIM) + l32);
                acc.x += bf2f(h0.x) + bf2f(h1.x) + bf2f(h2.x) + bf2f(h3.x)
                       + bf2f(h4.x) + bf2f(h5.x) + bf2f(h6.x) + bf2f(h7.x);
                acc.y += bf2f(h0.y) + bf2f(h1.y) + bf2f(h2.y) + bf2f(h3.y)
                       + bf2f(h4.y) + bf2f(h5.y) + bf2f(h6.y) + bf2f(h7.y);
                acc.z += bf2f(h0.z) + bf2f(h1.z) + bf2f(h2.z) + bf2f(h3.z)
                       + bf2f(h4.z) + bf2f(h5.z) + bf2f(h6.z) + bf2f(h7.z);
                acc.w += bf2f(h0.w) + bf2f(h1.w) + bf2f(h2.w) + bf2f(h3.w)
                       + bf2f(h4.w) + bf2f(h5.w) + bf2f(h6.w) + bf2f(h7.w);
            }
            for (; j < cnt; ++j) {
                int s0 = __shfl(idx, j, 32);
                ushort4 h0 = *((const ushort4*)(Hs + (size_t)s0 * FDIM) + l32);
                acc.x += bf2f(h0.x); acc.y += bf2f(h0.y);
                acc.z += bf2f(h0.z); acc.w += bf2f(h0.w);
            }
        }
        float4 v;
        v.x = fmaxf(fmaf(acc.x, dd, b4.x), 0.f);
        v.y = fmaxf(fmaf(acc.y, dd, b4.y), 0.f);
        v.z = fmaxf(fmaf(acc.z, dd, b4.z), 0.f);
        v.w = fmaxf(fmaf(acc.w, dd, b4.w), 0.f);
        *((float4*)(Xout + (size_t)d * FDIM) + l32) = v;
        stS.x += v.x; stS.y += v.y; stS.z += v.z; stS.w += v.w;
        stS2.x = fmaf(v.x, v.x, stS2.x);
        stS2.y = fmaf(v.y, v.y, stS2.y);
        stS2.z = fmaf(v.z, v.z, stS2.z);
        stS2.w = fmaf(v.w, v.w, stS2.w);
    }

    *((float4*)&redS[ng][l32 * 4])  = stS;
    *((float4*)&redS2[ng][l32 * 4]) = stS2;
    __syncthreads();
    if (tid < FDIM) {
        float a = 0.f;
#pragma unroll
        for (int g = 0; g < 8; ++g) a += redS[g][tid];
        unsafeAtomicAdd(&sum[tid], a);
    } else {
        int f = tid - FDIM;
        float a = 0.f;
#pragma unroll
        for (int g = 0; g < 8; ++g) a += redS2[g][f];
        unsafeAtomicAdd(&sumsq[f], a);
    }
}

// ---------------------------------------------------------------------------
// Segment max; BN(a,b) recomputed per-thread from stats (thread == feature)
// ---------------------------------------------------------------------------
__global__ void k_segmax(const float* __restrict__ X, const int* __restrict__ ibatch,
                         const float* __restrict__ sum, const float* __restrict__ ssq,
                         const float* __restrict__ gamma, const float* __restrict__ beta,
                         float* __restrict__ out) {
    int g = blockIdx.x;
    int f = threadIdx.x;
    __shared__ int bounds[2];
    if (threadIdx.x < 2) {
        int target = g + (int)threadIdx.x;
        int lo = 0, hi = NNODES;
        while (lo < hi) {
            int mid = (lo + hi) >> 1;
            if (ibatch[mid] < target) lo = mid + 1; else hi = mid;
        }
        bounds[threadIdx.x] = lo;
    }
    float mu  = sum[f] * (1.f / NNODES);
    float var = ssq[f] * (1.f / NNODES) - mu * mu;
    float af = gamma[f] * rsqrtf(var + BN_EPS);
    float bf = beta[f] - mu * af;
    __syncthreads();
    float m = -INFINITY;
    for (int r = bounds[0]; r < bounds[1]; ++r)
        m = fmaxf(m, fmaf(X[(size_t)r * FDIM + f], af, bf));
    out[g * FDIM + f] = m;
}

// ---------------------------------------------------------------------------
// Fused branch layer 1 (chem K=256 | tgt K=2048 | cell K=1024), one launch.
// Y = tanh(X @ W + bias) + per-feature stats.  Row counts divide exactly.
// ---------------------------------------------------------------------------
template<int K, int R>
__device__ void branch_l1_body(int blk, const float* __restrict__ X,
                               const float* __restrict__ W, const float* __restrict__ bias,
                               float* __restrict__ Y, float* __restrict__ sum,
                               float* __restrict__ sumsq, float* xs) {
    int f = threadIdx.x;
    int row0 = blk * R;
    for (int t = threadIdx.x; t < R * K; t += 128) {
        int r = t / K, k = t - r * K;
        xs[t] = X[(size_t)(row0 + r) * K + k];
    }
    __syncthreads();
    float acc[R];
#pragma unroll
    for (int r = 0; r < R; ++r) acc[r] = 0.f;
    for (int k = 0; k < K; ++k) {
        float w = W[k * FDIM + f];
#pragma unroll
        for (int r = 0; r < R; ++r) acc[r] = fmaf(xs[r * K + k], w, acc[r]);
    }
    float bf = bias[f];
    float s = 0.f, s2 = 0.f;
#pragma unroll
    for (int r = 0; r < R; ++r) {
        float v = tanhf(acc[r] + bf);
        Y[(size_t)(row0 + r) * FDIM + f] = v;
        s += v;
        s2 = fmaf(v, v, s2);
    }
    unsafeAtomicAdd(&sum[f], s);
    unsafeAtomicAdd(&sumsq[f], s2);
}

__global__ __launch_bounds__(128) void k_branch_l1_all(
        const float* Xch, const float* Wch, const float* bch,
        const float* Xtg, const float* Wtg, const float* btg,
        const float* Xcl, const float* Wcl, const float* bcl,
        float* Ych, float* Ytg, float* Ycl,
        float* sum_ch, float* ssq_ch, float* sum_tg, float* ssq_tg,
        float* sum_cl, float* ssq_cl) {
    extern __shared__ float xs[];
    int b = blockIdx.x;
    if (b < 128)      branch_l1_body<256, 16>(b,       Xch, Wch, bch, Ych, sum_ch, ssq_ch, xs);
    else if (b < 640) branch_l1_body<2048, 4>(b - 128, Xtg, Wtg, btg, Ytg, sum_tg, ssq_tg, xs);
    else              branch_l1_body<1024, 8>(b - 640, Xcl, Wcl, bcl, Ycl, sum_cl, ssq_cl, xs);
}

// ---------------------------------------------------------------------------
// Fused branch layer 2 (x3), BN recomputed in-prologue:
//   out = relu((Y*a+b) @ W + bias)
// ---------------------------------------------------------------------------
template<int R>
__device__ void branch_l2_body(int blk, const float* __restrict__ Y,
                               const float* __restrict__ sum, const float* __restrict__ ssq,
                               const float* __restrict__ gamma, const float* __restrict__ beta,
                               const float* __restrict__ W, const float* __restrict__ bias,
                               float* __restrict__ out, float* xs, float* sa, float* sb) {
    int f = threadIdx.x;
    {
        float mu  = sum[f] * (1.f / NBATCH);
        float var = ssq[f] * (1.f / NBATCH) - mu * mu;
        float a = gamma[f] * rsqrtf(var + BN_EPS);
        sa[f] = a;
        sb[f] = beta[f] - mu * a;
    }
    __syncthreads();
    int row0 = blk * R;
    for (int t = threadIdx.x; t < R * FDIM; t += 128) {
        int r = t >> 7, k = t & 127;
        xs[t] = fmaf(Y[(size_t)(row0 + r) * FDIM + k], sa[k], sb[k]);
    }
    __syncthreads();
    float acc[R];
#pragma unroll
    for (int r = 0; r < R; ++r) acc[r] = 0.f;
    for (int k = 0; k < FDIM; ++k) {
        float w = W[k * FDIM + f];
#pragma unroll
        for (int r = 0; r < R; ++r) acc[r] = fmaf(xs[r * FDIM + k], w, acc[r]);
    }
    float bf = bias[f];
#pragma unroll
    for (int r = 0; r < R; ++r)
        out[(size_t)(row0 + r) * FDIM + f] = fmaxf(acc[r] + bf, 0.f);
}

__global__ __launch_bounds__(128) void k_branch_l2_all(
        const float* Ych, const float* sum_ch, const float* ssq_ch,
        const float* gch, const float* bech, const float* Wch, const float* bch, float* och,
        const float* Ytg, const float* sum_tg, const float* ssq_tg,
        const float* gtg, const float* betg, const float* Wtg, const float* btg, float* otg,
        const float* Ycl, const float* sum_cl, const float* ssq_cl,
        const float* gcl, const float* becl, const float* Wcl, const float* bcl, float* ocl) {
    __shared__ float xs[16 * FDIM];
    __shared__ float sa[FDIM], sb[FDIM];
    int b = blockIdx.x;
    if (b < 128)      branch_l2_body<16>(b,       Ych, sum_ch, ssq_ch, gch, bech, Wch, bch, och, xs, sa, sb);
    else if (b < 256) branch_l2_body<16>(b - 128, Ytg, sum_tg, ssq_tg, gtg, betg, Wtg, btg, otg, xs, sa, sb);
    else              branch_l2_body<16>(b - 256, Ycl, sum_cl, ssq_cl, gcl, becl, Wcl, bcl, ocl, xs, sa, sb);
}

// ---------------------------------------------------------------------------
extern "C" void kernel_launch(void* const* d_in, const int* in_sizes, int n_in,
                              void* d_out, int out_size, void* d_ws, size_t ws_size,
                              hipStream_t stream) {
    const float* Xs    = (const float*)d_in[0];
    const int*   adj   = (const int*)d_in[1];
    const int*   esrc  = adj;
    const int*   edst  = adj + NEDGES;
    const int*   ibat  = (const int*)d_in[2];
    const float* Xchem = (const float*)d_in[3];
    const float* Xtgt  = (const float*)d_in[4];
    const float* Xcell = (const float*)d_in[5];
    const float* Wc1 = (const float*)d_in[6],  *bc1 = (const float*)d_in[7];
    const float* g1  = (const float*)d_in[8],  *be1 = (const float*)d_in[9];
    const float* Wc2 = (const float*)d_in[10], *bc2 = (const float*)d_in[11];
    const float* g2  = (const float*)d_in[12], *be2 = (const float*)d_in[13];
    const float* Wh1 = (const float*)d_in[14], *bh1 = (const float*)d_in[15];
    const float* gh  = (const float*)d_in[16], *beh = (const float*)d_in[17];
    const float* Wh2 = (const float*)d_in[18], *bh2 = (const float*)d_in[19];
    const float* Wt1 = (const float*)d_in[20], *bt1 = (const float*)d_in[21];
    const float* gt  = (const float*)d_in[22], *bet = (const float*)d_in[23];
    const float* Wt2 = (const float*)d_in[24], *bt2 = (const float*)d_in[25];
    const float* Wg1 = (const float*)d_in[26], *bg1 = (const float*)d_in[27];
    const float* gg  = (const float*)d_in[28], *beg = (const float*)d_in[29];
    const float* Wg2 = (const float*)d_in[30], *bg2 = (const float*)d_in[31];

    // workspace layout
    float*          Xbuf = (float*)d_ws;                           // N*128 fp32
    unsigned short* Hbf  = (unsigned short*)(Xbuf + (size_t)NNODES * FDIM); // N*128 bf16
    unsigned* deg  = (unsigned*)(Hbf + (size_t)NNODES * FDIM);     // N u32
    float*    dinv = (float*)(deg + NNODES);                       // N f32
    int*      rowStart = (int*)(dinv + NNODES);                    // N+1
    int*      cursor   = rowStart + NNODES + 1;                    // N
    unsigned* tsum = (unsigned*)(cursor + NNODES);                 // SCAN_T
    unsigned* toff = tsum + SCAN_T;                                // SCAN_T
    int*      csr_src = (int*)(toff + SCAN_T);                     // E
    float*    stats = (float*)(csr_src + NEDGES);                  // 5*256
    float*    ybuf_ch = stats + 5 * 256;                           // 2048*128
    float*    ybuf_tg = ybuf_ch + (size_t)NBATCH * FDIM;           // 2048*128
    float*    ybuf_cl = ybuf_tg + (size_t)NBATCH * FDIM;           // 2048*128

    float* sum_g1 = stats + 0 * 256, *ssq_g1 = sum_g1 + 128;
    float* sum_g2 = stats + 1 * 256, *ssq_g2 = sum_g2 + 128;
    float* sum_ch = stats + 2 * 256, *ssq_ch = sum_ch + 128;
    float* sum_tg = stats + 3 * 256, *ssq_tg = sum_tg + 128;
    float* sum_cl = stats + 4 * 256, *ssq_cl = sum_cl + 128;

    float* out_stru = (float*)d_out;
    float* out_chem = out_stru + (size_t)NBATCH * FDIM;
    float* out_tgt  = out_chem + (size_t)NBATCH * FDIM;
    float* out_cell = out_tgt + (size_t)NBATCH * FDIM;

    // --- degree + norm + CSR build ---
    k_init<<<(NNODES + 255) / 256, 256, 0, stream>>>(deg, stats, 5 * 256);
    k_deg<<<(NEDGES + 255) / 256, 256, 0, stream>>>(edst, deg);
    k_scan1<<<SCAN_T / 256, 256, 0, stream>>>(deg, tsum, dinv);
    k_scan2<<<1, SCAN_T, 0, stream>>>(tsum, toff);
    k_scan3<<<SCAN_T / 256, 256, 0, stream>>>(deg, toff, rowStart, cursor);
    k_scatter<<<(NEDGES + 255) / 256, 256, 0, stream>>>(esrc, edst, cursor, csr_src);

    // --- GCN layer 1 ---
    k_gcn_gemm1<78, 16><<<NNODES / 16, 128, 0, stream>>>(Xs, Wc1, dinv, Hbf);
    k_gather_fin<<<GB_BLOCKS, 256, 0, stream>>>(Hbf, rowStart, csr_src, dinv,
                                                bc1, Xbuf, sum_g1, ssq_g1);

    // --- GCN layer 2 (BN1 folded in-kernel) ---
    k_gcn_gemm2<16><<<NNODES / 16, 128, 0, stream>>>(Xbuf, sum_g1, ssq_g1, g1, be1,
                                                     Wc2, dinv, Hbf);
    k_gather_fin<<<GB_BLOCKS, 256, 0, stream>>>(Hbf, rowStart, csr_src, dinv,
                                                bc2, Xbuf, sum_g2, ssq_g2);

    // --- segment max (BN2 folded in-kernel) ---
    k_segmax<<<NBATCH, 128, 0, stream>>>(Xbuf, ibat, sum_g2, ssq_g2, g2, be2, out_stru);

    // --- fused branch layer 1 (chem 128 | tgt 512 | cell 256 blocks) ---
    k_branch_l1_all<<<896, 128, 32768, stream>>>(
        Xchem, Wh1, bh1, Xtgt, Wt1, bt1, Xcell, Wg1, bg1,
        ybuf_ch, ybuf_tg, ybuf_cl,
        sum_ch, ssq_ch, sum_tg, ssq_tg, sum_cl, ssq_cl);

    // --- fused branch layer 2 (BN folded in-kernel) ---
    k_branch_l2_all<<<384, 128, 0, stream>>>(
        ybuf_ch, sum_ch, ssq_ch, gh, beh, Wh2, bh2, out_chem,
        ybuf_tg, sum_tg, ssq_tg, gt, bet, Wt2, bt2, out_tgt,
        ybuf_cl, sum_cl, ssq_cl, gg, beg, Wg2, bg2, out_cell);
}

// Round 5
// 865.047 us; speedup vs baseline: 7.4743x; 1.1851x over previous
//
#include <hip/hip_runtime.h>
#include <hip/hip_bf16.h>
#include <math.h>

#define NNODES 100000
#define NEDGES 1600000
#define NBATCH 2048
#define FDIM   128
#define BN_EPS 1e-5f

#define SCAN_T 1024
#define CHUNK  ((NNODES + SCAN_T - 1) / SCAN_T)

#define GB_BLOCKS  3125
#define GB_BATCHES 12500

#define K1PAD 96          // GCN layer-1 K (78) padded to multiple of 32

typedef unsigned short ushort_t;
typedef short  bf16x8 __attribute__((ext_vector_type(8)));
typedef float  f32x4  __attribute__((ext_vector_type(4)));

// bf16 helpers (RNE)
__device__ __forceinline__ unsigned short f2bf(float x) {
    unsigned u = __float_as_uint(x);
    u += 0x7fff + ((u >> 16) & 1);
    return (unsigned short)(u >> 16);
}
__device__ __forceinline__ float bf2f(unsigned short s) {
    return __uint_as_float((unsigned)s << 16);
}
__device__ __forceinline__ bf16x8 pack8(float4 a, float4 b) {
    bf16x8 r;
    r[0] = (short)f2bf(a.x); r[1] = (short)f2bf(a.y);
    r[2] = (short)f2bf(a.z); r[3] = (short)f2bf(a.w);
    r[4] = (short)f2bf(b.x); r[5] = (short)f2bf(b.y);
    r[6] = (short)f2bf(b.z); r[7] = (short)f2bf(b.w);
    return r;
}

// ---------------------------------------------------------------------------
// init: deg = 1 (self loop), zero stats
// ---------------------------------------------------------------------------
__global__ void k_init(unsigned* __restrict__ deg, float* __restrict__ stats, int nstats) {
    int i = blockIdx.x * 256 + threadIdx.x;
    if (i < NNODES) deg[i] = 1u;
    if (i < nstats) stats[i] = 0.f;
}

__global__ void k_deg(const int* __restrict__ dst, unsigned* __restrict__ deg) {
    int e = blockIdx.x * 256 + threadIdx.x;
    if (e < NEDGES) atomicAdd(&deg[dst[e]], 1u);
}

// ---------------------------------------------------------------------------
// CSR build (scan + counting sort); dinv fused into scan1
// ---------------------------------------------------------------------------
__global__ void k_scan1(const unsigned* __restrict__ deg, unsigned* __restrict__ tsum,
                        float* __restrict__ dinv) {
    int i = blockIdx.x * 256 + threadIdx.x;
    int lo = i * CHUNK, hi = min(lo + CHUNK, NNODES);
    unsigned s = 0;
    for (int e = lo; e < hi; ++e) {
        unsigned dg = deg[e];
        dinv[e] = rsqrtf((float)dg);
        s += dg - 1u;
    }
    tsum[i] = s;
}

__global__ void k_scan2(const unsigned* __restrict__ tsum, unsigned* __restrict__ toff) {
    __shared__ unsigned sh[SCAN_T];
    int t = threadIdx.x;
    sh[t] = tsum[t];
    __syncthreads();
    for (int off = 1; off < SCAN_T; off <<= 1) {
        unsigned v = (t >= off) ? sh[t - off] : 0u;
        __syncthreads();
        sh[t] += v;
        __syncthreads();
    }
    toff[t] = (t == 0) ? 0u : sh[t - 1];
}

__global__ void k_scan3(const unsigned* __restrict__ deg, const unsigned* __restrict__ toff,
                        int* __restrict__ rowStart, int* __restrict__ cursor) {
    int i = blockIdx.x * 256 + threadIdx.x;
    int lo = i * CHUNK, hi = min(lo + CHUNK, NNODES);
    unsigned run = toff[i];
    for (int e = lo; e < hi; ++e) {
        rowStart[e] = (int)run;
        cursor[e]   = (int)run;
        run += deg[e] - 1u;
    }
    if (i == SCAN_T - 1) rowStart[NNODES] = NEDGES;
}

__global__ void k_scatter(const int* __restrict__ src, const int* __restrict__ dst,
                          int* __restrict__ cursor, int* __restrict__ csr_src) {
    int e = blockIdx.x * 256 + threadIdx.x;
    if (e < NEDGES) {
        int d = dst[e];
        int pos = atomicAdd(&cursor[d], 1);
        csr_src[pos] = src[e];
    }
}

// ---------------------------------------------------------------------------
// prep: Xs fp32 [N][78] -> bf16 padded [N][96]
// ---------------------------------------------------------------------------
__global__ void k_prepXs(const float* __restrict__ X, ushort_t* __restrict__ Xb) {
    int i = blockIdx.x * 256 + threadIdx.x;           // over NNODES*96
    int row = i / K1PAD, k = i - row * K1PAD;
    Xb[i] = (k < 78) ? f2bf(X[row * 78 + k]) : (ushort_t)0;
}

// ---------------------------------------------------------------------------
// prep: layer-1 weights -> bf16 fragment layout [k/8][n][8]
// segments: Fc1 96x128 (pad from 78) | Fh1 256x128 | Ft1 2048x128 | Fg1 1024x128
// ---------------------------------------------------------------------------
__global__ void k_prepW1(const float* __restrict__ Wc1, const float* __restrict__ Wh1,
                         const float* __restrict__ Wt1, const float* __restrict__ Wg1,
                         ushort_t* __restrict__ Fc1, ushort_t* __restrict__ Fh1,
                         ushort_t* __restrict__ Ft1, ushort_t* __restrict__ Fg1) {
    int i = blockIdx.x * 256 + threadIdx.x;           // total 438272
    const float* W; ushort_t* F; int Ksrc;
    if (i < 12288)       { W = Wc1; F = Fc1; Ksrc = 78; }
    else if (i < 45056)  { i -= 12288;  W = Wh1; F = Fh1; Ksrc = 256; }
    else if (i < 307200) { i -= 45056;  W = Wt1; F = Ft1; Ksrc = 2048; }
    else                 { i -= 307200; W = Wg1; F = Fg1; Ksrc = 1024; }
    int j = i & 7, n = (i >> 3) & 127, kblk = i >> 10;
    int k = kblk * 8 + j;
    F[i] = (k < Ksrc) ? f2bf(W[k * 128 + n]) : (ushort_t)0;
}

// ---------------------------------------------------------------------------
// foldW: bake batchnorm into a 128x128 weight matrix:
//   Bfrag[k][n] = a[k]*W[k][n] (bf16 frag layout), c[n] = sum_k b[k]*W[k][n] (+bias2)
// one block of 128 threads per fold
// ---------------------------------------------------------------------------
__device__ void foldW_body(const float* sum, const float* ssq, const float* gamma,
                           const float* beta, const float* W, const float* bias2,
                           float invN, ushort_t* Bfrag, float* cOut) {
    __shared__ float sa[128], sb[128];
    int t = threadIdx.x;
    float mu  = sum[t] * invN;
    float var = ssq[t] * invN - mu * mu;
    float a = gamma[t] * rsqrtf(var + BN_EPS);
    sa[t] = a;
    sb[t] = beta[t] - mu * a;
    __syncthreads();
    float c = bias2 ? bias2[t] : 0.f;
    for (int k = 0; k < 128; ++k) {
        float w = W[k * 128 + t];
        Bfrag[((k >> 3) * 128 + t) * 8 + (k & 7)] = f2bf(sa[k] * w);
        c = fmaf(sb[k], w, c);
    }
    cOut[t] = c;
}

__global__ void k_foldW_g2(const float* sum, const float* ssq, const float* gamma,
                           const float* beta, const float* W,
                           ushort_t* Bfrag, float* cOut) {
    foldW_body(sum, ssq, gamma, beta, W, nullptr, 1.f / NNODES, Bfrag, cOut);
}

__global__ void k_foldW3(const float* s_ch, const float* q_ch, const float* g_ch, const float* b_ch,
                         const float* W_ch, const float* bias_ch, ushort_t* F_ch, float* c_ch,
                         const float* s_tg, const float* q_tg, const float* g_tg, const float* b_tg,
                         const float* W_tg, const float* bias_tg, ushort_t* F_tg, float* c_tg,
                         const float* s_cl, const float* q_cl, const float* g_cl, const float* b_cl,
                         const float* W_cl, const float* bias_cl, ushort_t* F_cl, float* c_cl) {
    if (blockIdx.x == 0)
        foldW_body(s_ch, q_ch, g_ch, b_ch, W_ch, bias_ch, 1.f / NBATCH, F_ch, c_ch);
    else if (blockIdx.x == 1)
        foldW_body(s_tg, q_tg, g_tg, b_tg, W_tg, bias_tg, 1.f / NBATCH, F_tg, c_tg);
    else
        foldW_body(s_cl, q_cl, g_cl, b_cl, W_cl, bias_cl, 1.f / NBATCH, F_cl, c_cl);
}

// ---------------------------------------------------------------------------
// MFMA GEMM 1: Hs = bf16( (Xs_b @ Wc1) * dinv[row] )
// block = 512 thr = 8 waves; 16 rows x 128 cols per block; 6250 blocks
// ---------------------------------------------------------------------------
__global__ __launch_bounds__(512) void k_gemm1_mfma(
        const ushort_t* __restrict__ A,      // [N][96] bf16
        const ushort_t* __restrict__ B,      // frag [12][128][8]
        const float* __restrict__ dinv,
        ushort_t* __restrict__ Hout) {       // [N][128] bf16 pre-scaled
    int lane = threadIdx.x & 63, wave = threadIdx.x >> 6;
    int m = lane & 15, q = lane >> 4;
    int row0 = blockIdx.x * 16, n0 = wave * 16;
    f32x4 acc = {0.f, 0.f, 0.f, 0.f};
    const ushort_t* ap = A + (size_t)(row0 + m) * K1PAD + q * 8;
    const ushort_t* bp = B + ((size_t)q * 128 + n0 + m) * 8;
#pragma unroll
    for (int kc = 0; kc < K1PAD; kc += 32) {
        bf16x8 av = *(const bf16x8*)(ap + kc);
        bf16x8 bv = *(const bf16x8*)(bp + (size_t)(kc >> 3) * 1024);
        acc = __builtin_amdgcn_mfma_f32_16x16x32_bf16(av, bv, acc, 0, 0, 0);
    }
#pragma unroll
    for (int r = 0; r < 4; ++r) {
        int row = row0 + q * 4 + r;
        Hout[(size_t)row * FDIM + n0 + m] = f2bf(acc[r] * dinv[row]);
    }
}

// ---------------------------------------------------------------------------
// MFMA GEMM 2: Hs = bf16( (X1b @ W') * dinv + c*dinv )   (BN folded into W',c)
// ---------------------------------------------------------------------------
__global__ __launch_bounds__(512) void k_gemm2_mfma(
        const ushort_t* __restrict__ A,      // [N][128] bf16
        const ushort_t* __restrict__ B,      // frag [16][128][8]
        const float* __restrict__ cvec,
        const float* __restrict__ dinv,
        ushort_t* __restrict__ Hout) {
    int lane = threadIdx.x & 63, wave = threadIdx.x >> 6;
    int m = lane & 15, q = lane >> 4;
    int row0 = blockIdx.x * 16, n0 = wave * 16;
    f32x4 acc = {0.f, 0.f, 0.f, 0.f};
    const ushort_t* ap = A + (size_t)(row0 + m) * FDIM + q * 8;
    const ushort_t* bp = B + ((size_t)q * 128 + n0 + m) * 8;
#pragma unroll
    for (int kc = 0; kc < FDIM; kc += 32) {
        bf16x8 av = *(const bf16x8*)(ap + kc);
        bf16x8 bv = *(const bf16x8*)(bp + (size_t)(kc >> 3) * 1024);
        acc = __builtin_amdgcn_mfma_f32_16x16x32_bf16(av, bv, acc, 0, 0, 0);
    }
    float c = cvec[n0 + m];
#pragma unroll
    for (int r = 0; r < 4; ++r) {
        int row = row0 + q * 4 + r;
        Hout[(size_t)row * FDIM + n0 + m] = f2bf((acc[r] + c) * dinv[row]);
    }
}

// ---------------------------------------------------------------------------
// CSR gather + finalize over bf16 rows; OUTPUT bf16 now.
//   out[d] = relu(dinv[d]*(Hs[d] + sum_nbr Hs[s]) + bias); stats fp32
// ---------------------------------------------------------------------------
__global__ __launch_bounds__(256) void k_gather_fin(
        const ushort_t* __restrict__ Hs, const int* __restrict__ rowStart,
        const int* __restrict__ csr_src, const float* __restrict__ dinv,
        const float* __restrict__ bias, ushort_t* __restrict__ Xout,
        float* __restrict__ sum, float* __restrict__ sumsq) {
    __shared__ float redS[8][FDIM];
    __shared__ float redS2[8][FDIM];
    int tid = threadIdx.x;
    int ng  = tid >> 5;
    int l32 = tid & 31;

    const float4 b4 = *((const float4*)bias + l32);
    float4 stS  = {0.f, 0.f, 0.f, 0.f};
    float4 stS2 = {0.f, 0.f, 0.f, 0.f};

    for (int batch = blockIdx.x; batch < GB_BATCHES; batch += GB_BLOCKS) {
        int d = batch * 8 + ng;
        float dd = dinv[d];
        ushort4 hs = *((const ushort4*)(Hs + (size_t)d * FDIM) + l32);
        float4 acc = {bf2f(hs.x), bf2f(hs.y), bf2f(hs.z), bf2f(hs.w)};
        int lo = rowStart[d], hi = rowStart[d + 1];
        for (int base = lo; base < hi; base += 32) {
            int cnt = hi - base; if (cnt > 32) cnt = 32;
            int idx = 0;
            if (base + l32 < hi) idx = csr_src[base + l32];
            int j = 0;
            for (; j + 8 <= cnt; j += 8) {
                int s0 = __shfl(idx, j + 0, 32);
                int s1 = __shfl(idx, j + 1, 32);
                int s2 = __shfl(idx, j + 2, 32);
                int s3 = __shfl(idx, j + 3, 32);
                int s4 = __shfl(idx, j + 4, 32);
                int s5 = __shfl(idx, j + 5, 32);
                int s6 = __shfl(idx, j + 6, 32);
                int s7 = __shfl(idx, j + 7, 32);
                ushort4 h0 = *((const ushort4*)(Hs + (size_t)s0 * FDIM) + l32);
                ushort4 h1 = *((const ushort4*)(Hs + (size_t)s1 * FDIM) + l32);
                ushort4 h2 = *((const ushort4*)(Hs + (size_t)s2 * FDIM) + l32);
                ushort4 h3 = *((const ushort4*)(Hs + (size_t)s3 * FDIM) + l32);
                ushort4 h4 = *((const ushort4*)(Hs + (size_t)s4 * FDIM) + l32);
                ushort4 h5 = *((const ushort4*)(Hs + (size_t)s5 * FDIM) + l32);
                ushort4 h6 = *((const ushort4*)(Hs + (size_t)s6 * FDIM) + l32);
                ushort4 h7 = *((const ushort4*)(Hs + (size_t)s7 * FDIM) + l32);
                acc.x += bf2f(h0.x) + bf2f(h1.x) + bf2f(h2.x) + bf2f(h3.x)
                       + bf2f(h4.x) + bf2f(h5.x) + bf2f(h6.x) + bf2f(h7.x);
                acc.y += bf2f(h0.y) + bf2f(h1.y) + bf2f(h2.y) + bf2f(h3.y)
                       + bf2f(h4.y) + bf2f(h5.y) + bf2f(h6.y) + bf2f(h7.y);
                acc.z += bf2f(h0.z) + bf2f(h1.z) + bf2f(h2.z) + bf2f(h3.z)
                       + bf2f(h4.z) + bf2f(h5.z) + bf2f(h6.z) + bf2f(h7.z);
                acc.w += bf2f(h0.w) + bf2f(h1.w) + bf2f(h2.w) + bf2f(h3.w)
                       + bf2f(h4.w) + bf2f(h5.w) + bf2f(h6.w) + bf2f(h7.w);
            }
            for (; j < cnt; ++j) {
                int s0 = __shfl(idx, j, 32);
                ushort4 h0 = *((const ushort4*)(Hs + (size_t)s0 * FDIM) + l32);
                acc.x += bf2f(h0.x); acc.y += bf2f(h0.y);
                acc.z += bf2f(h0.z); acc.w += bf2f(h0.w);
            }
        }
        float4 v;
        v.x = fmaxf(fmaf(acc.x, dd, b4.x), 0.f);
        v.y = fmaxf(fmaf(acc.y, dd, b4.y), 0.f);
        v.z = fmaxf(fmaf(acc.z, dd, b4.z), 0.f);
        v.w = fmaxf(fmaf(acc.w, dd, b4.w), 0.f);
        ushort4 o = {f2bf(v.x), f2bf(v.y), f2bf(v.z), f2bf(v.w)};
        *((ushort4*)(Xout + (size_t)d * FDIM) + l32) = o;
        stS.x += v.x; stS.y += v.y; stS.z += v.z; stS.w += v.w;
        stS2.x = fmaf(v.x, v.x, stS2.x);
        stS2.y = fmaf(v.y, v.y, stS2.y);
        stS2.z = fmaf(v.z, v.z, stS2.z);
        stS2.w = fmaf(v.w, v.w, stS2.w);
    }

    *((float4*)&redS[ng][l32 * 4])  = stS;
    *((float4*)&redS2[ng][l32 * 4]) = stS2;
    __syncthreads();
    if (tid < FDIM) {
        float a = 0.f;
#pragma unroll
        for (int g = 0; g < 8; ++g) a += redS[g][tid];
        unsafeAtomicAdd(&sum[tid], a);
    } else {
        int f = tid - FDIM;
        float a = 0.f;
#pragma unroll
        for (int g = 0; g < 8; ++g) a += redS2[g][f];
        unsafeAtomicAdd(&sumsq[f], a);
    }
}

// ---------------------------------------------------------------------------
// Segment max over bf16 X; BN recomputed per-thread from stats
// ---------------------------------------------------------------------------
__global__ void k_segmax(const ushort_t* __restrict__ X, const int* __restrict__ ibatch,
                         const float* __restrict__ sum, const float* __restrict__ ssq,
                         const float* __restrict__ gamma, const float* __restrict__ beta,
                         float* __restrict__ out) {
    int g = blockIdx.x;
    int f = threadIdx.x;
    __shared__ int bounds[2];
    if (threadIdx.x < 2) {
        int target = g + (int)threadIdx.x;
        int lo = 0, hi = NNODES;
        while (lo < hi) {
            int mid = (lo + hi) >> 1;
            if (ibatch[mid] < target) lo = mid + 1; else hi = mid;
        }
        bounds[threadIdx.x] = lo;
    }
    float mu  = sum[f] * (1.f / NNODES);
    float var = ssq[f] * (1.f / NNODES) - mu * mu;
    float af = gamma[f] * rsqrtf(var + BN_EPS);
    float bf = beta[f] - mu * af;
    __syncthreads();
    float m = -INFINITY;
    for (int r = bounds[0]; r < bounds[1]; ++r)
        m = fmaxf(m, fmaf(bf2f(X[(size_t)r * FDIM + f]), af, bf));
    out[g * FDIM + f] = m;
}

// ---------------------------------------------------------------------------
// Fused MFMA branch layer 1: Y = bf16(tanh(X @ W1 + bias)) + stats
// A loaded fp32 (float4 x2) and converted in-register.
// blocks: 0-127 chem(K=256) | 128-255 cell(K=1024) | 256-383 tgt(K=2048)
// ---------------------------------------------------------------------------
template<int K>
__device__ void branch_l1_mfma(int tile, const float* __restrict__ X,
                               const ushort_t* __restrict__ B,
                               const float* __restrict__ bias,
                               ushort_t* __restrict__ Y,
                               float* __restrict__ sum, float* __restrict__ sumsq) {
    int lane = threadIdx.x & 63, wave = threadIdx.x >> 6;
    int m = lane & 15, q = lane >> 4;
    int row0 = tile * 16, n0 = wave * 16;
    f32x4 acc = {0.f, 0.f, 0.f, 0.f};
    const float* ap = X + (size_t)(row0 + m) * K + q * 8;
    const ushort_t* bp = B + ((size_t)q * 128 + n0 + m) * 8;
    for (int kc = 0; kc < K; kc += 32) {
        float4 a0 = *(const float4*)(ap + kc);
        float4 a1 = *(const float4*)(ap + kc + 4);
        bf16x8 av = pack8(a0, a1);
        bf16x8 bv = *(const bf16x8*)(bp + (size_t)(kc >> 3) * 1024);
        acc = __builtin_amdgcn_mfma_f32_16x16x32_bf16(av, bv, acc, 0, 0, 0);
    }
    int n = n0 + m;
    float bb = bias[n];
    float s = 0.f, s2 = 0.f;
#pragma unroll
    for (int r = 0; r < 4; ++r) {
        float v = tanhf(acc[r] + bb);
        Y[(size_t)(row0 + q * 4 + r) * FDIM + n] = f2bf(v);
        s += v;
        s2 = fmaf(v, v, s2);
    }
    s  += __shfl_xor(s, 16);  s  += __shfl_xor(s, 32);
    s2 += __shfl_xor(s2, 16); s2 += __shfl_xor(s2, 32);
    if (q == 0) {
        unsafeAtomicAdd(&sum[n], s);
        unsafeAtomicAdd(&sumsq[n], s2);
    }
}

__global__ __launch_bounds__(512) void k_branch_l1_mfma(
        const float* Xch, const ushort_t* Fch, const float* bch, ushort_t* Ych,
        float* sum_ch, float* ssq_ch,
        const float* Xcl, const ushort_t* Fcl, const float* bcl, ushort_t* Ycl,
        float* sum_cl, float* ssq_cl,
        const float* Xtg, const ushort_t* Ftg, const float* btg, ushort_t* Ytg,
        float* sum_tg, float* ssq_tg) {
    int b = blockIdx.x;
    if (b < 128)      branch_l1_mfma<256>(b,       Xch, Fch, bch, Ych, sum_ch, ssq_ch);
    else if (b < 256) branch_l1_mfma<1024>(b - 128, Xcl, Fcl, bcl, Ycl, sum_cl, ssq_cl);
    else              branch_l1_mfma<2048>(b - 256, Xtg, Ftg, btg, Ytg, sum_tg, ssq_tg);
}

// ---------------------------------------------------------------------------
// Fused MFMA branch layer 2: out = relu(Y @ W' + c)  (BN+bias folded)
// ---------------------------------------------------------------------------
__device__ void branch_l2_mfma(int tile, const ushort_t* __restrict__ Y,
                               const ushort_t* __restrict__ B,
                               const float* __restrict__ cvec,
                               float* __restrict__ out) {
    int lane = threadIdx.x & 63, wave = threadIdx.x >> 6;
    int m = lane & 15, q = lane >> 4;
    int row0 = tile * 16, n0 = wave * 16;
    f32x4 acc = {0.f, 0.f, 0.f, 0.f};
    const ushort_t* ap = Y + (size_t)(row0 + m) * FDIM + q * 8;
    const ushort_t* bp = B + ((size_t)q * 128 + n0 + m) * 8;
#pragma unroll
    for (int kc = 0; kc < FDIM; kc += 32) {
        bf16x8 av = *(const bf16x8*)(ap + kc);
        bf16x8 bv = *(const bf16x8*)(bp + (size_t)(kc >> 3) * 1024);
        acc = __builtin_amdgcn_mfma_f32_16x16x32_bf16(av, bv, acc, 0, 0, 0);
    }
    int n = n0 + m;
    float c = cvec[n];
#pragma unroll
    for (int r = 0; r < 4; ++r)
        out[(size_t)(row0 + q * 4 + r) * FDIM + n] = fmaxf(acc[r] + c, 0.f);
}

__global__ __launch_bounds__(512) void k_branch_l2_mfma(
        const ushort_t* Ych, const ushort_t* Fch, const float* cch, float* och,
        const ushort_t* Ycl, const ushort_t* Fcl, const float* ccl, float* ocl,
        const ushort_t* Ytg, const ushort_t* Ftg, const float* ctg, float* otg) {
    int b = blockIdx.x;
    if (b < 128)      branch_l2_mfma(b,       Ych, Fch, cch, och);
    else if (b < 256) branch_l2_mfma(b - 128, Ycl, Fcl, ccl, ocl);
    else              branch_l2_mfma(b - 256, Ytg, Ftg, ctg, otg);
}

// ---------------------------------------------------------------------------
extern "C" void kernel_launch(void* const* d_in, const int* in_sizes, int n_in,
                              void* d_out, int out_size, void* d_ws, size_t ws_size,
                              hipStream_t stream) {
    const float* Xs    = (const float*)d_in[0];
    const int*   adj   = (const int*)d_in[1];
    const int*   esrc  = adj;
    const int*   edst  = adj + NEDGES;
    const int*   ibat  = (const int*)d_in[2];
    const float* Xchem = (const float*)d_in[3];
    const float* Xtgt  = (const float*)d_in[4];
    const float* Xcell = (const float*)d_in[5];
    const float* Wc1 = (const float*)d_in[6],  *bc1 = (const float*)d_in[7];
    const float* g1  = (const float*)d_in[8],  *be1 = (const float*)d_in[9];
    const float* Wc2 = (const float*)d_in[10], *bc2 = (const float*)d_in[11];
    const float* g2  = (const float*)d_in[12], *be2 = (const float*)d_in[13];
    const float* Wh1 = (const float*)d_in[14], *bh1 = (const float*)d_in[15];
    const float* gh  = (const float*)d_in[16], *beh = (const float*)d_in[17];
    const float* Wh2 = (const float*)d_in[18], *bh2 = (const float*)d_in[19];
    const float* Wt1 = (const float*)d_in[20], *bt1 = (const float*)d_in[21];
    const float* gt  = (const float*)d_in[22], *bet = (const float*)d_in[23];
    const float* Wt2 = (const float*)d_in[24], *bt2 = (const float*)d_in[25];
    const float* Wg1 = (const float*)d_in[26], *bg1 = (const float*)d_in[27];
    const float* gg  = (const float*)d_in[28], *beg = (const float*)d_in[29];
    const float* Wg2 = (const float*)d_in[30], *bg2 = (const float*)d_in[31];

    // ---- workspace layout (bf16 region first; all chunks 16B-multiples) ----
    ushort_t* Xs_b = (ushort_t*)d_ws;                       // N*96
    ushort_t* Hbf  = Xs_b + (size_t)NNODES * K1PAD;         // N*128
    ushort_t* X1b  = Hbf  + (size_t)NNODES * FDIM;          // N*128
    ushort_t* X2b  = X1b  + (size_t)NNODES * FDIM;          // N*128
    ushort_t* Fc1  = X2b  + (size_t)NNODES * FDIM;          // 12*128*8   = 12288
    ushort_t* Fh1  = Fc1 + 12288;                           // 32*128*8   = 32768
    ushort_t* Ft1  = Fh1 + 32768;                           // 256*128*8  = 262144
    ushort_t* Fg1  = Ft1 + 262144;                          // 128*128*8  = 131072
    ushort_t* Fc2  = Fg1 + 131072;                          // 16*128*8   = 16384
    ushort_t* Fh2  = Fc2 + 16384;
    ushort_t* Ft2  = Fh2 + 16384;
    ushort_t* Fg2  = Ft2 + 16384;
    ushort_t* Ych  = Fg2 + 16384;                           // B*128
    ushort_t* Ytg  = Ych + (size_t)NBATCH * FDIM;
    ushort_t* Ycl  = Ytg + (size_t)NBATCH * FDIM;
    unsigned* deg  = (unsigned*)(Ycl + (size_t)NBATCH * FDIM); // N
    float*    dinv = (float*)(deg + NNODES);                // N
    int*      rowStart = (int*)(dinv + NNODES);             // N+1
    int*      cursor   = rowStart + NNODES + 1;             // N
    unsigned* tsum = (unsigned*)(cursor + NNODES);          // SCAN_T
    unsigned* toff = tsum + SCAN_T;                         // SCAN_T
    int*      csr_src = (int*)(toff + SCAN_T);              // E
    float*    stats = (float*)(csr_src + NEDGES);           // 5*256
    float*    cvec  = stats + 5 * 256;                      // 4*128

    float* sum_g1 = stats + 0 * 256, *ssq_g1 = sum_g1 + 128;
    float* sum_g2 = stats + 1 * 256, *ssq_g2 = sum_g2 + 128;
    float* sum_ch = stats + 2 * 256, *ssq_ch = sum_ch + 128;
    float* sum_tg = stats + 3 * 256, *ssq_tg = sum_tg + 128;
    float* sum_cl = stats + 4 * 256, *ssq_cl = sum_cl + 128;
    float* c_g2 = cvec + 0 * 128;
    float* c_ch = cvec + 1 * 128;
    float* c_tg = cvec + 2 * 128;
    float* c_cl = cvec + 3 * 128;

    float* out_stru = (float*)d_out;
    float* out_chem = out_stru + (size_t)NBATCH * FDIM;
    float* out_tgt  = out_chem + (size_t)NBATCH * FDIM;
    float* out_cell = out_tgt + (size_t)NBATCH * FDIM;

    // --- prep (independent) ---
    k_prepXs<<<(NNODES * K1PAD) / 256, 256, 0, stream>>>(Xs, Xs_b);
    k_prepW1<<<438272 / 256, 256, 0, stream>>>(Wc1, Wh1, Wt1, Wg1, Fc1, Fh1, Ft1, Fg1);

    // --- degree + norm + CSR build ---
    k_init<<<(NNODES + 255) / 256, 256, 0, stream>>>(deg, stats, 5 * 256);
    k_deg<<<(NEDGES + 255) / 256, 256, 0, stream>>>(edst, deg);
    k_scan1<<<SCAN_T / 256, 256, 0, stream>>>(deg, tsum, dinv);
    k_scan2<<<1, SCAN_T, 0, stream>>>(tsum, toff);
    k_scan3<<<SCAN_T / 256, 256, 0, stream>>>(deg, toff, rowStart, cursor);
    k_scatter<<<(NEDGES + 255) / 256, 256, 0, stream>>>(esrc, edst, cursor, csr_src);

    // --- GCN layer 1 ---
    k_gemm1_mfma<<<NNODES / 16, 512, 0, stream>>>(Xs_b, Fc1, dinv, Hbf);
    k_gather_fin<<<GB_BLOCKS, 256, 0, stream>>>(Hbf, rowStart, csr_src, dinv,
                                                bc1, X1b, sum_g1, ssq_g1);

    // --- GCN layer 2 (BN1 folded into weights) ---
    k_foldW_g2<<<1, 128, 0, stream>>>(sum_g1, ssq_g1, g1, be1, Wc2, Fc2, c_g2);
    k_gemm2_mfma<<<NNODES / 16, 512, 0, stream>>>(X1b, Fc2, c_g2, dinv, Hbf);
    k_gather_fin<<<GB_BLOCKS, 256, 0, stream>>>(Hbf, rowStart, csr_src, dinv,
                                                bc2, X2b, sum_g2, ssq_g2);

    // --- segment max (BN2 in-kernel) ---
    k_segmax<<<NBATCH, 128, 0, stream>>>(X2b, ibat, sum_g2, ssq_g2, g2, be2, out_stru);

    // --- branches: MFMA layer 1 (fused), fold BN into W2, MFMA layer 2 ---
    k_branch_l1_mfma<<<384, 512, 0, stream>>>(
        Xchem, Fh1, bh1, Ych, sum_ch, ssq_ch,
        Xcell, Fg1, bg1, Ycl, sum_cl, ssq_cl,
        Xtgt,  Ft1, bt1, Ytg, sum_tg, ssq_tg);
    k_foldW3<<<3, 128, 0, stream>>>(
        sum_ch, ssq_ch, gh, beh, Wh2, bh2, Fh2, c_ch,
        sum_tg, ssq_tg, gt, bet, Wt2, bt2, Ft2, c_tg,
        sum_cl, ssq_cl, gg, beg, Wg2, bg2, Fg2, c_cl);
    k_branch_l2_mfma<<<384, 512, 0, stream>>>(
        Ych, Fh2, c_ch, out_chem,
        Ycl, Fg2, c_cl, out_cell,
        Ytg, Ft2, c_tg, out_tgt);
}

// Round 6
// 814.363 us; speedup vs baseline: 7.9395x; 1.0622x over previous
//
#include <hip/hip_runtime.h>
#include <hip/hip_bf16.h>
#include <math.h>

#define NNODES 100000
#define NEDGES 1600000
#define NBATCH 2048
#define FDIM   128
#define BN_EPS 1e-5f

#define SCAN_T 1024
#define CHUNK  ((NNODES + SCAN_T - 1) / SCAN_T)

#define GB_BLOCKS   1250          // gather blocks (5 batches each)
#define GB_BATCHES  6250          // 16 nodes per batch
#define CSRP_MAX    3200000       // NEDGES + 16*NNODES upper bound

#define K1PAD 96                  // GCN layer-1 K (78) padded to 96

typedef unsigned short ushort_t;
typedef short    bf16x8 __attribute__((ext_vector_type(8)));
typedef ushort_t us8    __attribute__((ext_vector_type(8)));
typedef float    f32x4  __attribute__((ext_vector_type(4)));

// bf16 helpers (RNE)
__device__ __forceinline__ unsigned short f2bf(float x) {
    unsigned u = __float_as_uint(x);
    u += 0x7fff + ((u >> 16) & 1);
    return (unsigned short)(u >> 16);
}
__device__ __forceinline__ float bf2f(unsigned short s) {
    return __uint_as_float((unsigned)s << 16);
}
__device__ __forceinline__ bf16x8 pack8(float4 a, float4 b) {
    bf16x8 r;
    r[0] = (short)f2bf(a.x); r[1] = (short)f2bf(a.y);
    r[2] = (short)f2bf(a.z); r[3] = (short)f2bf(a.w);
    r[4] = (short)f2bf(b.x); r[5] = (short)f2bf(b.y);
    r[6] = (short)f2bf(b.z); r[7] = (short)f2bf(b.w);
    return r;
}

// ---------------------------------------------------------------------------
// fill padded CSR array with the zero-row index (NNODES)
// ---------------------------------------------------------------------------
__global__ void k_fillcsr(int* __restrict__ p) {
    p[blockIdx.x * 256 + threadIdx.x] = NNODES;
}

__global__ void k_deg(const int* __restrict__ dst, unsigned* __restrict__ deg) {
    int e = blockIdx.x * 256 + threadIdx.x;
    if (e < NEDGES) atomicAdd(&deg[dst[e]], 1u);
}

// ---------------------------------------------------------------------------
// CSR build with per-node padding to multiples of 16.
// deg[] holds IN-EDGE counts (self loop excluded); dinv = rsqrt(deg+1).
// ---------------------------------------------------------------------------
__global__ void k_scan1(const unsigned* __restrict__ deg, unsigned* __restrict__ tsum,
                        float* __restrict__ dinv) {
    int i = blockIdx.x * 256 + threadIdx.x;
    int lo = i * CHUNK, hi = min(lo + CHUNK, NNODES);
    unsigned s = 0;
    for (int e = lo; e < hi; ++e) {
        unsigned dg = deg[e];
        dinv[e] = rsqrtf((float)(dg + 1u));
        s += (dg + 15u) & ~15u;            // padded length
    }
    tsum[i] = s;
}

__global__ void k_scan2(const unsigned* __restrict__ tsum, unsigned* __restrict__ toff) {
    __shared__ unsigned sh[SCAN_T];
    int t = threadIdx.x;
    sh[t] = tsum[t];
    __syncthreads();
    for (int off = 1; off < SCAN_T; off <<= 1) {
        unsigned v = (t >= off) ? sh[t - off] : 0u;
        __syncthreads();
        sh[t] += v;
        __syncthreads();
    }
    toff[t] = (t == 0) ? 0u : sh[t - 1];
}

__global__ void k_scan3(const unsigned* __restrict__ deg, const unsigned* __restrict__ toff,
                        int* __restrict__ rowStartP, int* __restrict__ cursor) {
    int i = blockIdx.x * 256 + threadIdx.x;
    int lo = i * CHUNK, hi = min(lo + CHUNK, NNODES);
    unsigned run = toff[i];
    for (int e = lo; e < hi; ++e) {
        rowStartP[e] = (int)run;
        cursor[e]    = (int)run;
        run += (deg[e] + 15u) & ~15u;
    }
    if (i == SCAN_T - 1) rowStartP[NNODES] = (int)run;
}

__global__ void k_scatter(const int* __restrict__ src, const int* __restrict__ dst,
                          int* __restrict__ cursor, int* __restrict__ csrP) {
    int e = blockIdx.x * 256 + threadIdx.x;
    if (e < NEDGES) {
        int d = dst[e];
        int pos = atomicAdd(&cursor[d], 1);
        csrP[pos] = src[e];
    }
}

// ---------------------------------------------------------------------------
// prep: Xs fp32 [N][78] -> bf16 padded [N][96]
// ---------------------------------------------------------------------------
__global__ void k_prepXs(const float* __restrict__ X, ushort_t* __restrict__ Xb) {
    int i = blockIdx.x * 256 + threadIdx.x;
    int row = i / K1PAD, k = i - row * K1PAD;
    Xb[i] = (k < 78) ? f2bf(X[row * 78 + k]) : (ushort_t)0;
}

// ---------------------------------------------------------------------------
// prep: layer-1 weights -> bf16 fragment layout [k/8][n][8]
// ---------------------------------------------------------------------------
__global__ void k_prepW1(const float* __restrict__ Wc1, const float* __restrict__ Wh1,
                         const float* __restrict__ Wt1, const float* __restrict__ Wg1,
                         ushort_t* __restrict__ Fc1, ushort_t* __restrict__ Fh1,
                         ushort_t* __restrict__ Ft1, ushort_t* __restrict__ Fg1) {
    int i = blockIdx.x * 256 + threadIdx.x;           // total 438272
    const float* W; ushort_t* F; int Ksrc;
    if (i < 12288)       { W = Wc1; F = Fc1; Ksrc = 78; }
    else if (i < 45056)  { i -= 12288;  W = Wh1; F = Fh1; Ksrc = 256; }
    else if (i < 307200) { i -= 45056;  W = Wt1; F = Ft1; Ksrc = 2048; }
    else                 { i -= 307200; W = Wg1; F = Fg1; Ksrc = 1024; }
    int j = i & 7, n = (i >> 3) & 127, kblk = i >> 10;
    int k = kblk * 8 + j;
    F[i] = (k < Ksrc) ? f2bf(W[k * 128 + n]) : (ushort_t)0;
}

// ---------------------------------------------------------------------------
// Parallel BN-fold into 128x128 weights:
//   blocks 0..63 : Bfrag[k][n] = a[k]*W[k][n] (frag layout, bf16)
//   block  64    : c[n] = bias2[n] + sum_k b[k]*W[k][n]
// ---------------------------------------------------------------------------
__device__ __forceinline__ void fold_frag_elem(int i, const float* sum, const float* ssq,
                                               const float* gamma, float invN,
                                               const float* W, ushort_t* F) {
    int n = i & 127, k = i >> 7;
    float mu  = sum[k] * invN;
    float var = ssq[k] * invN - mu * mu;
    float a = gamma[k] * rsqrtf(var + BN_EPS);
    F[((size_t)(k >> 3) * 128 + n) * 8 + (k & 7)] = f2bf(a * W[k * 128 + n]);
}

__device__ __forceinline__ void fold_c_elem(const float* sum, const float* ssq,
                                            const float* gamma, const float* beta,
                                            float invN, const float* W,
                                            const float* bias2, float* cOut, float* sb) {
    int t = threadIdx.x;            // 0..127
    float mu  = sum[t] * invN;
    float var = ssq[t] * invN - mu * mu;
    float a = gamma[t] * rsqrtf(var + BN_EPS);
    sb[t] = beta[t] - mu * a;
    __syncthreads();
    float c0 = 0.f, c1 = 0.f, c2 = 0.f, c3 = 0.f;
#pragma unroll
    for (int k = 0; k < 128; k += 4) {
        c0 = fmaf(sb[k + 0], W[(k + 0) * 128 + t], c0);
        c1 = fmaf(sb[k + 1], W[(k + 1) * 128 + t], c1);
        c2 = fmaf(sb[k + 2], W[(k + 2) * 128 + t], c2);
        c3 = fmaf(sb[k + 3], W[(k + 3) * 128 + t], c3);
    }
    cOut[t] = (bias2 ? bias2[t] : 0.f) + (c0 + c1) + (c2 + c3);
}

__global__ void k_fold_g2(const float* sum, const float* ssq, const float* gamma,
                          const float* beta, const float* W,
                          ushort_t* F, float* cOut) {
    __shared__ float sb[128];
    int b = blockIdx.x;
    if (b < 64)
        fold_frag_elem(b * 256 + threadIdx.x, sum, ssq, gamma, 1.f / NNODES, W, F);
    else if (threadIdx.x < 128)
        fold_c_elem(sum, ssq, gamma, beta, 1.f / NNODES, W, nullptr, cOut, sb);
}

__global__ void k_fold3(const float* s0, const float* q0, const float* g0, const float* b0,
                        const float* W0, const float* bi0, ushort_t* F0, float* c0,
                        const float* s1, const float* q1, const float* g1, const float* b1,
                        const float* W1, const float* bi1, ushort_t* F1, float* c1,
                        const float* s2, const float* q2, const float* g2, const float* b2,
                        const float* W2, const float* bi2, ushort_t* F2, float* c2) {
    __shared__ float sb[128];
    int b = blockIdx.x;
    int which = b / 65, role = b % 65;
    const float *sum, *ssq, *gamma, *beta, *W, *bias2; ushort_t* F; float* cOut;
    if (which == 0) { sum = s0; ssq = q0; gamma = g0; beta = b0; W = W0; bias2 = bi0; F = F0; cOut = c0; }
    else if (which == 1) { sum = s1; ssq = q1; gamma = g1; beta = b1; W = W1; bias2 = bi1; F = F1; cOut = c1; }
    else { sum = s2; ssq = q2; gamma = g2; beta = b2; W = W2; bias2 = bi2; F = F2; cOut = c2; }
    if (role < 64)
        fold_frag_elem(role * 256 + threadIdx.x, sum, ssq, gamma, 1.f / NBATCH, W, F);
    else if (threadIdx.x < 128)
        fold_c_elem(sum, ssq, gamma, beta, 1.f / NBATCH, W, bias2, cOut, sb);
}

// ---------------------------------------------------------------------------
// MFMA GEMM 1: Hs = bf16( (Xs_b @ Wc1) * dinv[row] ); also zeros pad row N
// ---------------------------------------------------------------------------
__global__ __launch_bounds__(512) void k_gemm1_mfma(
        const ushort_t* __restrict__ A,      // [N][96]
        const ushort_t* __restrict__ B,      // frag [12][128][8]
        const float* __restrict__ dinv,
        ushort_t* __restrict__ Hout) {       // [N+1][128]
    if (blockIdx.x == 0 && threadIdx.x < FDIM)
        Hout[(size_t)NNODES * FDIM + threadIdx.x] = 0;   // zero pad row
    int lane = threadIdx.x & 63, wave = threadIdx.x >> 6;
    int m = lane & 15, q = lane >> 4;
    int row0 = blockIdx.x * 16, n0 = wave * 16;
    f32x4 acc = {0.f, 0.f, 0.f, 0.f};
    const ushort_t* ap = A + (size_t)(row0 + m) * K1PAD + q * 8;
    const ushort_t* bp = B + ((size_t)q * 128 + n0 + m) * 8;
#pragma unroll
    for (int kc = 0; kc < K1PAD; kc += 32) {
        bf16x8 av = *(const bf16x8*)(ap + kc);
        bf16x8 bv = *(const bf16x8*)(bp + (size_t)(kc >> 3) * 1024);
        acc = __builtin_amdgcn_mfma_f32_16x16x32_bf16(av, bv, acc, 0, 0, 0);
    }
#pragma unroll
    for (int r = 0; r < 4; ++r) {
        int row = row0 + q * 4 + r;
        Hout[(size_t)row * FDIM + n0 + m] = f2bf(acc[r] * dinv[row]);
    }
}

// ---------------------------------------------------------------------------
// MFMA GEMM 2: Hs = bf16( ((X1b @ W') + c) * dinv )   (BN folded into W',c)
// ---------------------------------------------------------------------------
__global__ __launch_bounds__(512) void k_gemm2_mfma(
        const ushort_t* __restrict__ A,      // [N][128]
        const ushort_t* __restrict__ B,      // frag [16][128][8]
        const float* __restrict__ cvec,
        const float* __restrict__ dinv,
        ushort_t* __restrict__ Hout) {
    if (blockIdx.x == 0 && threadIdx.x < FDIM)
        Hout[(size_t)NNODES * FDIM + threadIdx.x] = 0;
    int lane = threadIdx.x & 63, wave = threadIdx.x >> 6;
    int m = lane & 15, q = lane >> 4;
    int row0 = blockIdx.x * 16, n0 = wave * 16;
    f32x4 acc = {0.f, 0.f, 0.f, 0.f};
    const ushort_t* ap = A + (size_t)(row0 + m) * FDIM + q * 8;
    const ushort_t* bp = B + ((size_t)q * 128 + n0 + m) * 8;
#pragma unroll
    for (int kc = 0; kc < FDIM; kc += 32) {
        bf16x8 av = *(const bf16x8*)(ap + kc);
        bf16x8 bv = *(const bf16x8*)(bp + (size_t)(kc >> 3) * 1024);
        acc = __builtin_amdgcn_mfma_f32_16x16x32_bf16(av, bv, acc, 0, 0, 0);
    }
    float c = cvec[n0 + m];
#pragma unroll
    for (int r = 0; r < 4; ++r) {
        int row = row0 + q * 4 + r;
        Hout[(size_t)row * FDIM + n0 + m] = f2bf((acc[r] + c) * dinv[row]);
    }
}

// ---------------------------------------------------------------------------
// CSR gather + finalize, v3: 16-lane slots, ushort8 (one full 256B row per
// quarter-wave instruction = 4 rows/instr), CSR padded to multiples of 16
// with zero-row indices -> inner loop is a fully-unrolled 16-deep burst of
// independent loads, no tail, no per-edge branching.
//   out[d] = relu(dinv[d]*(Hs[d] + sum_nbr Hs[s]) + bias)
// ---------------------------------------------------------------------------
__global__ __launch_bounds__(256) void k_gather_fin(
        const ushort_t* __restrict__ Hs, const int* __restrict__ rowStartP,
        const int* __restrict__ csrP, const float* __restrict__ dinv,
        const float* __restrict__ bias, ushort_t* __restrict__ Xout,
        float* __restrict__ sum, float* __restrict__ sumsq) {
    __shared__ float redS[16][FDIM];
    __shared__ float redS2[16][FDIM];
    int tid = threadIdx.x;
    int ng  = tid >> 4;          // slot 0..15 (one node at a time)
    int l16 = tid & 15;          // lane in slot; owns 8 features
    int f0  = l16 * 8;

    float bl[8];
    {
        float4 ba = *(const float4*)(bias + f0);
        float4 bb = *(const float4*)(bias + f0 + 4);
        bl[0] = ba.x; bl[1] = ba.y; bl[2] = ba.z; bl[3] = ba.w;
        bl[4] = bb.x; bl[5] = bb.y; bl[6] = bb.z; bl[7] = bb.w;
    }
    float sS[8], sQ[8];
#pragma unroll
    for (int j = 0; j < 8; ++j) { sS[j] = 0.f; sQ[j] = 0.f; }

    for (int batch = blockIdx.x; batch < GB_BATCHES; batch += GB_BLOCKS) {
        int d = batch * 16 + ng;                 // 16*6250 == NNODES
        float dd = dinv[d];
        us8 h = *(const us8*)(Hs + (size_t)d * FDIM + f0);
        float acc[8];
#pragma unroll
        for (int j = 0; j < 8; ++j) acc[j] = bf2f(h[j]);

        int lo = rowStartP[d], hi = rowStartP[d + 1];
        for (int base = lo; base < hi; base += 16) {
            int idx = csrP[base + l16];          // 16 indices, coalesced
#pragma unroll
            for (int j = 0; j < 16; ++j) {
                int s = __shfl(idx, j, 16);
                us8 hv = *(const us8*)(Hs + (size_t)s * FDIM + f0);
#pragma unroll
                for (int t = 0; t < 8; ++t) acc[t] += bf2f(hv[t]);
            }
        }
        us8 o;
#pragma unroll
        for (int j = 0; j < 8; ++j) {
            float v = fmaxf(fmaf(acc[j], dd, bl[j]), 0.f);
            o[j] = f2bf(v);
            sS[j] += v;
            sQ[j] = fmaf(v, v, sQ[j]);
        }
        *(us8*)(Xout + (size_t)d * FDIM + f0) = o;
    }

#pragma unroll
    for (int j = 0; j < 8; ++j) { redS[ng][f0 + j] = sS[j]; redS2[ng][f0 + j] = sQ[j]; }
    __syncthreads();
    if (tid < FDIM) {
        float a = 0.f;
#pragma unroll
        for (int g = 0; g < 16; ++g) a += redS[g][tid];
        unsafeAtomicAdd(&sum[tid], a);
    } else {
        int f = tid - FDIM;
        float a = 0.f;
#pragma unroll
        for (int g = 0; g < 16; ++g) a += redS2[g][f];
        unsafeAtomicAdd(&sumsq[f], a);
    }
}

// ---------------------------------------------------------------------------
// Segment max over bf16 X; BN recomputed per-thread from stats
// ---------------------------------------------------------------------------
__global__ void k_segmax(const ushort_t* __restrict__ X, const int* __restrict__ ibatch,
                         const float* __restrict__ sum, const float* __restrict__ ssq,
                         const float* __restrict__ gamma, const float* __restrict__ beta,
                         float* __restrict__ out) {
    int g = blockIdx.x;
    int f = threadIdx.x;
    __shared__ int bounds[2];
    if (threadIdx.x < 2) {
        int target = g + (int)threadIdx.x;
        int lo = 0, hi = NNODES;
        while (lo < hi) {
            int mid = (lo + hi) >> 1;
            if (ibatch[mid] < target) lo = mid + 1; else hi = mid;
        }
        bounds[threadIdx.x] = lo;
    }
    float mu  = sum[f] * (1.f / NNODES);
    float var = ssq[f] * (1.f / NNODES) - mu * mu;
    float af = gamma[f] * rsqrtf(var + BN_EPS);
    float bf = beta[f] - mu * af;
    __syncthreads();
    float m = -INFINITY;
    for (int r = bounds[0]; r < bounds[1]; ++r)
        m = fmaxf(m, fmaf(bf2f(X[(size_t)r * FDIM + f]), af, bf));
    out[g * FDIM + f] = m;
}

// ---------------------------------------------------------------------------
// Fused MFMA branch layer 1: Y = bf16(tanh(X @ W1 + bias)) + stats
// ---------------------------------------------------------------------------
template<int K>
__device__ void branch_l1_mfma(int tile, const float* __restrict__ X,
                               const ushort_t* __restrict__ B,
                               const float* __restrict__ bias,
                               ushort_t* __restrict__ Y,
                               float* __restrict__ sum, float* __restrict__ sumsq) {
    int lane = threadIdx.x & 63, wave = threadIdx.x >> 6;
    int m = lane & 15, q = lane >> 4;
    int row0 = tile * 16, n0 = wave * 16;
    f32x4 acc = {0.f, 0.f, 0.f, 0.f};
    const float* ap = X + (size_t)(row0 + m) * K + q * 8;
    const ushort_t* bp = B + ((size_t)q * 128 + n0 + m) * 8;
    for (int kc = 0; kc < K; kc += 32) {
        float4 a0 = *(const float4*)(ap + kc);
        float4 a1 = *(const float4*)(ap + kc + 4);
        bf16x8 av = pack8(a0, a1);
        bf16x8 bv = *(const bf16x8*)(bp + (size_t)(kc >> 3) * 1024);
        acc = __builtin_amdgcn_mfma_f32_16x16x32_bf16(av, bv, acc, 0, 0, 0);
    }
    int n = n0 + m;
    float bb = bias[n];
    float s = 0.f, s2 = 0.f;
#pragma unroll
    for (int r = 0; r < 4; ++r) {
        float v = tanhf(acc[r] + bb);
        Y[(size_t)(row0 + q * 4 + r) * FDIM + n] = f2bf(v);
        s += v;
        s2 = fmaf(v, v, s2);
    }
    s  += __shfl_xor(s, 16);  s  += __shfl_xor(s, 32);
    s2 += __shfl_xor(s2, 16); s2 += __shfl_xor(s2, 32);
    if (q == 0) {
        unsafeAtomicAdd(&sum[n], s);
        unsafeAtomicAdd(&sumsq[n], s2);
    }
}

__global__ __launch_bounds__(512) void k_branch_l1_mfma(
        const float* Xch, const ushort_t* Fch, const float* bch, ushort_t* Ych,
        float* sum_ch, float* ssq_ch,
        const float* Xcl, const ushort_t* Fcl, const float* bcl, ushort_t* Ycl,
        float* sum_cl, float* ssq_cl,
        const float* Xtg, const ushort_t* Ftg, const float* btg, ushort_t* Ytg,
        float* sum_tg, float* ssq_tg) {
    int b = blockIdx.x;
    if (b < 128)      branch_l1_mfma<256>(b,        Xch, Fch, bch, Ych, sum_ch, ssq_ch);
    else if (b < 256) branch_l1_mfma<1024>(b - 128, Xcl, Fcl, bcl, Ycl, sum_cl, ssq_cl);
    else              branch_l1_mfma<2048>(b - 256, Xtg, Ftg, btg, Ytg, sum_tg, ssq_tg);
}

// ---------------------------------------------------------------------------
// Fused MFMA branch layer 2: out = relu(Y @ W' + c)   (BN+bias folded)
// ---------------------------------------------------------------------------
__device__ void branch_l2_mfma(int tile, const ushort_t* __restrict__ Y,
                               const ushort_t* __restrict__ B,
                               const float* __restrict__ cvec,
                               float* __restrict__ out) {
    int lane = threadIdx.x & 63, wave = threadIdx.x >> 6;
    int m = lane & 15, q = lane >> 4;
    int row0 = tile * 16, n0 = wave * 16;
    f32x4 acc = {0.f, 0.f, 0.f, 0.f};
    const ushort_t* ap = Y + (size_t)(row0 + m) * FDIM + q * 8;
    const ushort_t* bp = B + ((size_t)q * 128 + n0 + m) * 8;
#pragma unroll
    for (int kc = 0; kc < FDIM; kc += 32) {
        bf16x8 av = *(const bf16x8*)(ap + kc);
        bf16x8 bv = *(const bf16x8*)(bp + (size_t)(kc >> 3) * 1024);
        acc = __builtin_amdgcn_mfma_f32_16x16x32_bf16(av, bv, acc, 0, 0, 0);
    }
    int n = n0 + m;
    float c = cvec[n];
#pragma unroll
    for (int r = 0; r < 4; ++r)
        out[(size_t)(row0 + q * 4 + r) * FDIM + n] = fmaxf(acc[r] + c, 0.f);
}

__global__ __launch_bounds__(512) void k_branch_l2_mfma(
        const ushort_t* Ych, const ushort_t* Fch, const float* cch, float* och,
        const ushort_t* Ycl, const ushort_t* Fcl, const float* ccl, float* ocl,
        const ushort_t* Ytg, const ushort_t* Ftg, const float* ctg, float* otg) {
    int b = blockIdx.x;
    if (b < 128)      branch_l2_mfma(b,       Ych, Fch, cch, och);
    else if (b < 256) branch_l2_mfma(b - 128, Ycl, Fcl, ccl, ocl);
    else              branch_l2_mfma(b - 256, Ytg, Ftg, ctg, otg);
}

// ---------------------------------------------------------------------------
extern "C" void kernel_launch(void* const* d_in, const int* in_sizes, int n_in,
                              void* d_out, int out_size, void* d_ws, size_t ws_size,
                              hipStream_t stream) {
    const float* Xs    = (const float*)d_in[0];
    const int*   adj   = (const int*)d_in[1];
    const int*   esrc  = adj;
    const int*   edst  = adj + NEDGES;
    const int*   ibat  = (const int*)d_in[2];
    const float* Xchem = (const float*)d_in[3];
    const float* Xtgt  = (const float*)d_in[4];
    const float* Xcell = (const float*)d_in[5];
    const float* Wc1 = (const float*)d_in[6],  *bc1 = (const float*)d_in[7];
    const float* g1  = (const float*)d_in[8],  *be1 = (const float*)d_in[9];
    const float* Wc2 = (const float*)d_in[10], *bc2 = (const float*)d_in[11];
    const float* g2  = (const float*)d_in[12], *be2 = (const float*)d_in[13];
    const float* Wh1 = (const float*)d_in[14], *bh1 = (const float*)d_in[15];
    const float* gh  = (const float*)d_in[16], *beh = (const float*)d_in[17];
    const float* Wh2 = (const float*)d_in[18], *bh2 = (const float*)d_in[19];
    const float* Wt1 = (const float*)d_in[20], *bt1 = (const float*)d_in[21];
    const float* gt  = (const float*)d_in[22], *bet = (const float*)d_in[23];
    const float* Wt2 = (const float*)d_in[24], *bt2 = (const float*)d_in[25];
    const float* Wg1 = (const float*)d_in[26], *bg1 = (const float*)d_in[27];
    const float* gg  = (const float*)d_in[28], *beg = (const float*)d_in[29];
    const float* Wg2 = (const float*)d_in[30], *bg2 = (const float*)d_in[31];

    // ---- workspace layout ----
    ushort_t* Xs_b = (ushort_t*)d_ws;                        // N*96
    ushort_t* Hbf  = Xs_b + (size_t)NNODES * K1PAD;          // (N+1)*128
    ushort_t* X1b  = Hbf  + ((size_t)NNODES + 1) * FDIM;     // N*128
    ushort_t* X2b  = X1b  + (size_t)NNODES * FDIM;           // N*128
    ushort_t* Fc1  = X2b  + (size_t)NNODES * FDIM;           // 12288
    ushort_t* Fh1  = Fc1 + 12288;                            // 32768
    ushort_t* Ft1  = Fh1 + 32768;                            // 262144
    ushort_t* Fg1  = Ft1 + 262144;                           // 131072
    ushort_t* Fc2  = Fg1 + 131072;                           // 16384
    ushort_t* Fh2  = Fc2 + 16384;
    ushort_t* Ft2  = Fh2 + 16384;
    ushort_t* Fg2  = Ft2 + 16384;
    ushort_t* Ych  = Fg2 + 16384;                            // B*128
    ushort_t* Ytg  = Ych + (size_t)NBATCH * FDIM;
    ushort_t* Ycl  = Ytg + (size_t)NBATCH * FDIM;
    unsigned* deg  = (unsigned*)(Ycl + (size_t)NBATCH * FDIM); // N
    float*    dinv = (float*)(deg + NNODES);                 // N
    int*      rowStartP = (int*)(dinv + NNODES);             // N+1
    int*      cursor    = rowStartP + NNODES + 1;            // N
    unsigned* tsum = (unsigned*)(cursor + NNODES);           // SCAN_T
    unsigned* toff = tsum + SCAN_T;                          // SCAN_T
    int*      csrP = (int*)(toff + SCAN_T);                  // CSRP_MAX
    float*    stats = (float*)(csrP + CSRP_MAX);             // 5*256
    float*    cvec  = stats + 5 * 256;                       // 4*128

    float* sum_g1 = stats + 0 * 256, *ssq_g1 = sum_g1 + 128;
    float* sum_g2 = stats + 1 * 256, *ssq_g2 = sum_g2 + 128;
    float* sum_ch = stats + 2 * 256, *ssq_ch = sum_ch + 128;
    float* sum_tg = stats + 3 * 256, *ssq_tg = sum_tg + 128;
    float* sum_cl = stats + 4 * 256, *ssq_cl = sum_cl + 128;
    float* c_g2 = cvec + 0 * 128;
    float* c_ch = cvec + 1 * 128;
    float* c_tg = cvec + 2 * 128;
    float* c_cl = cvec + 3 * 128;

    float* out_stru = (float*)d_out;
    float* out_chem = out_stru + (size_t)NBATCH * FDIM;
    float* out_tgt  = out_chem + (size_t)NBATCH * FDIM;
    float* out_cell = out_tgt + (size_t)NBATCH * FDIM;

    // --- zero-init + prep (independent) ---
    hipMemsetAsync(deg, 0, NNODES * sizeof(unsigned), stream);
    hipMemsetAsync(stats, 0, 5 * 256 * sizeof(float), stream);
    k_fillcsr<<<CSRP_MAX / 256, 256, 0, stream>>>(csrP);
    k_prepXs<<<(NNODES * K1PAD) / 256, 256, 0, stream>>>(Xs, Xs_b);
    k_prepW1<<<438272 / 256, 256, 0, stream>>>(Wc1, Wh1, Wt1, Wg1, Fc1, Fh1, Ft1, Fg1);

    // --- degree + norm + padded CSR build ---
    k_deg<<<(NEDGES + 255) / 256, 256, 0, stream>>>(edst, deg);
    k_scan1<<<SCAN_T / 256, 256, 0, stream>>>(deg, tsum, dinv);
    k_scan2<<<1, SCAN_T, 0, stream>>>(tsum, toff);
    k_scan3<<<SCAN_T / 256, 256, 0, stream>>>(deg, toff, rowStartP, cursor);
    k_scatter<<<(NEDGES + 255) / 256, 256, 0, stream>>>(esrc, edst, cursor, csrP);

    // --- GCN layer 1 ---
    k_gemm1_mfma<<<NNODES / 16, 512, 0, stream>>>(Xs_b, Fc1, dinv, Hbf);
    k_gather_fin<<<GB_BLOCKS, 256, 0, stream>>>(Hbf, rowStartP, csrP, dinv,
                                                bc1, X1b, sum_g1, ssq_g1);

    // --- GCN layer 2 (BN1 folded into weights) ---
    k_fold_g2<<<65, 256, 0, stream>>>(sum_g1, ssq_g1, g1, be1, Wc2, Fc2, c_g2);
    k_gemm2_mfma<<<NNODES / 16, 512, 0, stream>>>(X1b, Fc2, c_g2, dinv, Hbf);
    k_gather_fin<<<GB_BLOCKS, 256, 0, stream>>>(Hbf, rowStartP, csrP, dinv,
                                                bc2, X2b, sum_g2, ssq_g2);

    // --- segment max (BN2 in-kernel) ---
    k_segmax<<<NBATCH, 128, 0, stream>>>(X2b, ibat, sum_g2, ssq_g2, g2, be2, out_stru);

    // --- branches ---
    k_branch_l1_mfma<<<384, 512, 0, stream>>>(
        Xchem, Fh1, bh1, Ych, sum_ch, ssq_ch,
        Xcell, Fg1, bg1, Ycl, sum_cl, ssq_cl,
        Xtgt,  Ft1, bt1, Ytg, sum_tg, ssq_tg);
    k_fold3<<<195, 256, 0, stream>>>(
        sum_ch, ssq_ch, gh, beh, Wh2, bh2, Fh2, c_ch,
        sum_tg, ssq_tg, gt, bet, Wt2, bt2, Ft2, c_tg,
        sum_cl, ssq_cl, gg, beg, Wg2, bg2, Fg2, c_cl);
    k_branch_l2_mfma<<<384, 512, 0, stream>>>(
        Ych, Fh2, c_ch, out_chem,
        Ycl, Fg2, c_cl, out_cell,
        Ytg, Ft2, c_tg, out_tgt);
}

// Round 7
// 702.605 us; speedup vs baseline: 9.2024x; 1.1591x over previous
//
#include <hip/hip_runtime.h>
#include <hip/hip_bf16.h>
#include <math.h>

#define NNODES 100000
#define NEDGES 1600000
#define NBATCH 2048
#define FDIM   128
#define BN_EPS 1e-5f

#define SCAN_T 1024
#define CHUNK  ((NNODES + SCAN_T - 1) / SCAN_T)

#define GB_BLOCKS   1250          // gather blocks (5 batches each)
#define GB_BATCHES  6250          // 16 nodes per batch
#define CSRP_MAX    3200000       // NEDGES + 16*NNODES upper bound

#define K1PAD 96                  // GCN layer-1 K (78) padded to 96

typedef unsigned short ushort_t;
typedef short    bf16x8 __attribute__((ext_vector_type(8)));
typedef ushort_t us8    __attribute__((ext_vector_type(8)));
typedef float    f32x4  __attribute__((ext_vector_type(4)));

// bf16 helpers (RNE)
__device__ __forceinline__ unsigned short f2bf(float x) {
    unsigned u = __float_as_uint(x);
    u += 0x7fff + ((u >> 16) & 1);
    return (unsigned short)(u >> 16);
}
__device__ __forceinline__ float bf2f(unsigned short s) {
    return __uint_as_float((unsigned)s << 16);
}
__device__ __forceinline__ bf16x8 pack8(float4 a, float4 b) {
    bf16x8 r;
    r[0] = (short)f2bf(a.x); r[1] = (short)f2bf(a.y);
    r[2] = (short)f2bf(a.z); r[3] = (short)f2bf(a.w);
    r[4] = (short)f2bf(b.x); r[5] = (short)f2bf(b.y);
    r[6] = (short)f2bf(b.z); r[7] = (short)f2bf(b.w);
    return r;
}

// ---------------------------------------------------------------------------
// MEGA-B: deg atomics | fill padded CSR | prep Xs->bf16 | prep W1 frags
// All independent; deg (latency/atomic-bound) overlaps the BW-bound preps.
// blocks: [0,6250) deg | [6250,18750) fillcsr | [18750,56250) prepXs |
//         [56250,57962) prepW1
// ---------------------------------------------------------------------------
__global__ __launch_bounds__(256) void k_megaB(
        const int* __restrict__ edst, unsigned* __restrict__ deg,
        int* __restrict__ csrP,
        const float* __restrict__ Xs, ushort_t* __restrict__ Xs_b,
        const float* __restrict__ Wc1, const float* __restrict__ Wh1,
        const float* __restrict__ Wt1, const float* __restrict__ Wg1,
        ushort_t* __restrict__ Fc1, ushort_t* __restrict__ Fh1,
        ushort_t* __restrict__ Ft1, ushort_t* __restrict__ Fg1) {
    int b = blockIdx.x;
    if (b < 6250) {
        int e = b * 256 + threadIdx.x;                 // 6250*256 == NEDGES
        atomicAdd(&deg[edst[e]], 1u);
    } else if (b < 18750) {
        int i = (b - 6250) * 256 + threadIdx.x;        // 12500*256 == CSRP_MAX
        csrP[i] = NNODES;
    } else if (b < 56250) {
        int i = (b - 18750) * 256 + threadIdx.x;       // 37500*256 == N*96
        int row = i / K1PAD, k = i - row * K1PAD;
        Xs_b[i] = (k < 78) ? f2bf(Xs[row * 78 + k]) : (ushort_t)0;
    } else {
        int i = (b - 56250) * 256 + threadIdx.x;       // 1712*256 == 438272
        const float* W; ushort_t* F; int Ksrc;
        if (i < 12288)       { W = Wc1; F = Fc1; Ksrc = 78; }
        else if (i < 45056)  { i -= 12288;  W = Wh1; F = Fh1; Ksrc = 256; }
        else if (i < 307200) { i -= 45056;  W = Wt1; F = Ft1; Ksrc = 2048; }
        else                 { i -= 307200; W = Wg1; F = Fg1; Ksrc = 1024; }
        int j = i & 7, n = (i >> 3) & 127, kblk = i >> 10;
        int k = kblk * 8 + j;
        F[i] = (k < Ksrc) ? f2bf(W[k * 128 + n]) : (ushort_t)0;
    }
}

// ---------------------------------------------------------------------------
// CSR build scans (padded to multiples of 16); dinv fused into scan1
// ---------------------------------------------------------------------------
__global__ void k_scan1(const unsigned* __restrict__ deg, unsigned* __restrict__ tsum,
                        float* __restrict__ dinv) {
    int i = blockIdx.x * 256 + threadIdx.x;
    int lo = i * CHUNK, hi = min(lo + CHUNK, NNODES);
    unsigned s = 0;
    for (int e = lo; e < hi; ++e) {
        unsigned dg = deg[e];
        dinv[e] = rsqrtf((float)(dg + 1u));
        s += (dg + 15u) & ~15u;
    }
    tsum[i] = s;
}

__global__ void k_scan2(const unsigned* __restrict__ tsum, unsigned* __restrict__ toff) {
    __shared__ unsigned sh[SCAN_T];
    int t = threadIdx.x;
    sh[t] = tsum[t];
    __syncthreads();
    for (int off = 1; off < SCAN_T; off <<= 1) {
        unsigned v = (t >= off) ? sh[t - off] : 0u;
        __syncthreads();
        sh[t] += v;
        __syncthreads();
    }
    toff[t] = (t == 0) ? 0u : sh[t - 1];
}

__global__ void k_scan3(const unsigned* __restrict__ deg, const unsigned* __restrict__ toff,
                        int* __restrict__ rowStartP, int* __restrict__ cursor) {
    int i = blockIdx.x * 256 + threadIdx.x;
    int lo = i * CHUNK, hi = min(lo + CHUNK, NNODES);
    unsigned run = toff[i];
    for (int e = lo; e < hi; ++e) {
        rowStartP[e] = (int)run;
        cursor[e]    = (int)run;
        run += (deg[e] + 15u) & ~15u;
    }
    if (i == SCAN_T - 1) rowStartP[NNODES] = (int)run;
}

// ---------------------------------------------------------------------------
// branch layer-1 MFMA body (shared by mega-A)
// ---------------------------------------------------------------------------
template<int K>
__device__ void branch_l1_mfma(int tile, const float* __restrict__ X,
                               const ushort_t* __restrict__ B,
                               const float* __restrict__ bias,
                               ushort_t* __restrict__ Y,
                               float* __restrict__ sum, float* __restrict__ sumsq) {
    int lane = threadIdx.x & 63, wave = threadIdx.x >> 6;
    int m = lane & 15, q = lane >> 4;
    int row0 = tile * 16, n0 = wave * 16;
    f32x4 acc = {0.f, 0.f, 0.f, 0.f};
    const float* ap = X + (size_t)(row0 + m) * K + q * 8;
    const ushort_t* bp = B + ((size_t)q * 128 + n0 + m) * 8;
    for (int kc = 0; kc < K; kc += 32) {
        float4 a0 = *(const float4*)(ap + kc);
        float4 a1 = *(const float4*)(ap + kc + 4);
        bf16x8 av = pack8(a0, a1);
        bf16x8 bv = *(const bf16x8*)(bp + (size_t)(kc >> 3) * 1024);
        acc = __builtin_amdgcn_mfma_f32_16x16x32_bf16(av, bv, acc, 0, 0, 0);
    }
    int n = n0 + m;
    float bb = bias[n];
    float s = 0.f, s2 = 0.f;
#pragma unroll
    for (int r = 0; r < 4; ++r) {
        float v = tanhf(acc[r] + bb);
        Y[(size_t)(row0 + q * 4 + r) * FDIM + n] = f2bf(v);
        s += v;
        s2 = fmaf(v, v, s2);
    }
    s  += __shfl_xor(s, 16);  s  += __shfl_xor(s, 32);
    s2 += __shfl_xor(s2, 16); s2 += __shfl_xor(s2, 32);
    if (q == 0) {
        unsafeAtomicAdd(&sum[n], s);
        unsafeAtomicAdd(&sumsq[n], s2);
    }
}

// ---------------------------------------------------------------------------
// MEGA-A: branch_l1 (MFMA) | scatter (atomic) x gemm1 (MFMA), interleaved.
// blocks: [0,384) branch_l1 | [384,9759): g=(b-384)/3, r=(b-384)%3,
//   r==0 -> scatter chunk g (512 edges), else -> gemm1 tile 2g+r-1
// ---------------------------------------------------------------------------
__global__ __launch_bounds__(512) void k_megaA(
        const int* __restrict__ esrc, const int* __restrict__ edst,
        int* __restrict__ cursor, int* __restrict__ csrP,
        const ushort_t* __restrict__ Xs_b, const ushort_t* __restrict__ Fc1,
        const float* __restrict__ dinv, ushort_t* __restrict__ Hout,
        const float* Xch, const ushort_t* Fch, const float* bch, ushort_t* Ych,
        float* sum_ch, float* ssq_ch,
        const float* Xcl, const ushort_t* Fcl, const float* bcl, ushort_t* Ycl,
        float* sum_cl, float* ssq_cl,
        const float* Xtg, const ushort_t* Ftg, const float* btg, ushort_t* Ytg,
        float* sum_tg, float* ssq_tg) {
    int b = blockIdx.x;
    if (b < 384) {
        if (b < 128)      branch_l1_mfma<256>(b,        Xch, Fch, bch, Ych, sum_ch, ssq_ch);
        else if (b < 256) branch_l1_mfma<1024>(b - 128, Xcl, Fcl, bcl, Ycl, sum_cl, ssq_cl);
        else              branch_l1_mfma<2048>(b - 256, Xtg, Ftg, btg, Ytg, sum_tg, ssq_tg);
        return;
    }
    int bb = b - 384;
    int g = bb / 3, r = bb - g * 3;
    if (r == 0) {
        // scatter: 512 edges
        int e = g * 512 + threadIdx.x;                 // 3125*512 == NEDGES
        int d = edst[e];
        int pos = atomicAdd(&cursor[d], 1);
        csrP[pos] = esrc[e];
    } else {
        int tile = 2 * g + (r - 1);                    // 0..6249
        if (tile == 0 && threadIdx.x < FDIM)
            Hout[(size_t)NNODES * FDIM + threadIdx.x] = 0;   // zero pad row
        int lane = threadIdx.x & 63, wave = threadIdx.x >> 6;
        int m = lane & 15, q = lane >> 4;
        int row0 = tile * 16, n0 = wave * 16;
        f32x4 acc = {0.f, 0.f, 0.f, 0.f};
        const ushort_t* ap = Xs_b + (size_t)(row0 + m) * K1PAD + q * 8;
        const ushort_t* bp = Fc1 + ((size_t)q * 128 + n0 + m) * 8;
#pragma unroll
        for (int kc = 0; kc < K1PAD; kc += 32) {
            bf16x8 av = *(const bf16x8*)(ap + kc);
            bf16x8 bv = *(const bf16x8*)(bp + (size_t)(kc >> 3) * 1024);
            acc = __builtin_amdgcn_mfma_f32_16x16x32_bf16(av, bv, acc, 0, 0, 0);
        }
#pragma unroll
        for (int rr = 0; rr < 4; ++rr) {
            int row = row0 + q * 4 + rr;
            Hout[(size_t)row * FDIM + n0 + m] = f2bf(acc[rr] * dinv[row]);
        }
    }
}

// ---------------------------------------------------------------------------
// Parallel BN-fold helpers
// ---------------------------------------------------------------------------
__device__ __forceinline__ void fold_frag_elem(int i, const float* sum, const float* ssq,
                                               const float* gamma, float invN,
                                               const float* W, ushort_t* F) {
    int n = i & 127, k = i >> 7;
    float mu  = sum[k] * invN;
    float var = ssq[k] * invN - mu * mu;
    float a = gamma[k] * rsqrtf(var + BN_EPS);
    F[((size_t)(k >> 3) * 128 + n) * 8 + (k & 7)] = f2bf(a * W[k * 128 + n]);
}

__device__ __forceinline__ void fold_c_elem(const float* sum, const float* ssq,
                                            const float* gamma, const float* beta,
                                            float invN, const float* W,
                                            const float* bias2, float* cOut, float* sb) {
    int t = threadIdx.x;            // 0..127
    float mu  = sum[t] * invN;
    float var = ssq[t] * invN - mu * mu;
    float a = gamma[t] * rsqrtf(var + BN_EPS);
    sb[t] = beta[t] - mu * a;
    __syncthreads();
    float c0 = 0.f, c1 = 0.f, c2 = 0.f, c3 = 0.f;
#pragma unroll
    for (int k = 0; k < 128; k += 4) {
        c0 = fmaf(sb[k + 0], W[(k + 0) * 128 + t], c0);
        c1 = fmaf(sb[k + 1], W[(k + 1) * 128 + t], c1);
        c2 = fmaf(sb[k + 2], W[(k + 2) * 128 + t], c2);
        c3 = fmaf(sb[k + 3], W[(k + 3) * 128 + t], c3);
    }
    cOut[t] = (bias2 ? bias2[t] : 0.f) + (c0 + c1) + (c2 + c3);
}

__global__ void k_fold_g2(const float* sum, const float* ssq, const float* gamma,
                          const float* beta, const float* W,
                          ushort_t* F, float* cOut) {
    __shared__ float sb[128];
    int b = blockIdx.x;
    if (b < 64)
        fold_frag_elem(b * 256 + threadIdx.x, sum, ssq, gamma, 1.f / NNODES, W, F);
    else if (threadIdx.x < 128)
        fold_c_elem(sum, ssq, gamma, beta, 1.f / NNODES, W, nullptr, cOut, sb);
}

// ---------------------------------------------------------------------------
// MFMA GEMM 2: Hs = bf16( ((X1b @ W') + c) * dinv )   (BN folded into W',c)
// ---------------------------------------------------------------------------
__global__ __launch_bounds__(512) void k_gemm2_mfma(
        const ushort_t* __restrict__ A, const ushort_t* __restrict__ B,
        const float* __restrict__ cvec, const float* __restrict__ dinv,
        ushort_t* __restrict__ Hout) {
    if (blockIdx.x == 0 && threadIdx.x < FDIM)
        Hout[(size_t)NNODES * FDIM + threadIdx.x] = 0;
    int lane = threadIdx.x & 63, wave = threadIdx.x >> 6;
    int m = lane & 15, q = lane >> 4;
    int row0 = blockIdx.x * 16, n0 = wave * 16;
    f32x4 acc = {0.f, 0.f, 0.f, 0.f};
    const ushort_t* ap = A + (size_t)(row0 + m) * FDIM + q * 8;
    const ushort_t* bp = B + ((size_t)q * 128 + n0 + m) * 8;
#pragma unroll
    for (int kc = 0; kc < FDIM; kc += 32) {
        bf16x8 av = *(const bf16x8*)(ap + kc);
        bf16x8 bv = *(const bf16x8*)(bp + (size_t)(kc >> 3) * 1024);
        acc = __builtin_amdgcn_mfma_f32_16x16x32_bf16(av, bv, acc, 0, 0, 0);
    }
    float c = cvec[n0 + m];
#pragma unroll
    for (int r = 0; r < 4; ++r) {
        int row = row0 + q * 4 + r;
        Hout[(size_t)row * FDIM + n0 + m] = f2bf((acc[r] + c) * dinv[row]);
    }
}

// ---------------------------------------------------------------------------
// CSR gather + finalize (16-lane slots, ushort8, padded CSR -> no tail)
// ---------------------------------------------------------------------------
__global__ __launch_bounds__(256) void k_gather_fin(
        const ushort_t* __restrict__ Hs, const int* __restrict__ rowStartP,
        const int* __restrict__ csrP, const float* __restrict__ dinv,
        const float* __restrict__ bias, ushort_t* __restrict__ Xout,
        float* __restrict__ sum, float* __restrict__ sumsq) {
    __shared__ float redS[16][FDIM];
    __shared__ float redS2[16][FDIM];
    int tid = threadIdx.x;
    int ng  = tid >> 4;
    int l16 = tid & 15;
    int f0  = l16 * 8;

    float bl[8];
    {
        float4 ba = *(const float4*)(bias + f0);
        float4 bb = *(const float4*)(bias + f0 + 4);
        bl[0] = ba.x; bl[1] = ba.y; bl[2] = ba.z; bl[3] = ba.w;
        bl[4] = bb.x; bl[5] = bb.y; bl[6] = bb.z; bl[7] = bb.w;
    }
    float sS[8], sQ[8];
#pragma unroll
    for (int j = 0; j < 8; ++j) { sS[j] = 0.f; sQ[j] = 0.f; }

    for (int batch = blockIdx.x; batch < GB_BATCHES; batch += GB_BLOCKS) {
        int d = batch * 16 + ng;
        float dd = dinv[d];
        us8 h = *(const us8*)(Hs + (size_t)d * FDIM + f0);
        float acc[8];
#pragma unroll
        for (int j = 0; j < 8; ++j) acc[j] = bf2f(h[j]);

        int lo = rowStartP[d], hi = rowStartP[d + 1];
        for (int base = lo; base < hi; base += 16) {
            int idx = csrP[base + l16];
#pragma unroll
            for (int j = 0; j < 16; ++j) {
                int s = __shfl(idx, j, 16);
                us8 hv = *(const us8*)(Hs + (size_t)s * FDIM + f0);
#pragma unroll
                for (int t = 0; t < 8; ++t) acc[t] += bf2f(hv[t]);
            }
        }
        us8 o;
#pragma unroll
        for (int j = 0; j < 8; ++j) {
            float v = fmaxf(fmaf(acc[j], dd, bl[j]), 0.f);
            o[j] = f2bf(v);
            sS[j] += v;
            sQ[j] = fmaf(v, v, sQ[j]);
        }
        *(us8*)(Xout + (size_t)d * FDIM + f0) = o;
    }

#pragma unroll
    for (int j = 0; j < 8; ++j) { redS[ng][f0 + j] = sS[j]; redS2[ng][f0 + j] = sQ[j]; }
    __syncthreads();
    if (tid < FDIM) {
        float a = 0.f;
#pragma unroll
        for (int g = 0; g < 16; ++g) a += redS[g][tid];
        unsafeAtomicAdd(&sum[tid], a);
    } else {
        int f = tid - FDIM;
        float a = 0.f;
#pragma unroll
        for (int g = 0; g < 16; ++g) a += redS2[g][f];
        unsafeAtomicAdd(&sumsq[f], a);
    }
}

// ---------------------------------------------------------------------------
// SEGFOLD: segmax (2 graphs/block, BN from stats) | fold3 (BN into W2 frags)
// blocks: [0,1024) segmax | [1024,1219) fold3
// ---------------------------------------------------------------------------
__global__ __launch_bounds__(256) void k_segfold(
        const ushort_t* __restrict__ X2b, const int* __restrict__ ibat,
        const float* sum_g2, const float* ssq_g2,
        const float* g2, const float* be2, float* __restrict__ out_stru,
        const float* s0, const float* q0, const float* g0, const float* b0,
        const float* W0, const float* bi0, ushort_t* F0, float* c0,
        const float* s1, const float* q1, const float* g1, const float* b1,
        const float* W1, const float* bi1, ushort_t* F1, float* c1,
        const float* s2, const float* q2, const float* g2_, const float* b2,
        const float* W2, const float* bi2, ushort_t* F2, float* c2) {
    __shared__ int bounds[2][2];
    __shared__ float sb[128];
    int b = blockIdx.x;
    if (b < 1024) {
        int half = threadIdx.x >> 7, f = threadIdx.x & 127;
        int g = b * 2 + half;
        if (f < 2) {
            int target = g + f;
            int lo = 0, hi = NNODES;
            while (lo < hi) {
                int mid = (lo + hi) >> 1;
                if (ibat[mid] < target) lo = mid + 1; else hi = mid;
            }
            bounds[half][f] = lo;
        }
        float mu  = sum_g2[f] * (1.f / NNODES);
        float var = ssq_g2[f] * (1.f / NNODES) - mu * mu;
        float af = g2[f] * rsqrtf(var + BN_EPS);
        float bf = be2[f] - mu * af;
        __syncthreads();
        float m = -INFINITY;
        int lo = bounds[half][0], hi = bounds[half][1];
        for (int r = lo; r < hi; ++r)
            m = fmaxf(m, fmaf(bf2f(X2b[(size_t)r * FDIM + f]), af, bf));
        out_stru[g * FDIM + f] = m;
    } else {
        int role = b - 1024;
        int which = role / 65, sub = role % 65;
        const float *sum, *ssq, *gamma, *beta, *W, *bias2; ushort_t* F; float* cOut;
        if (which == 0) { sum = s0; ssq = q0; gamma = g0; beta = b0; W = W0; bias2 = bi0; F = F0; cOut = c0; }
        else if (which == 1) { sum = s1; ssq = q1; gamma = g1; beta = b1; W = W1; bias2 = bi1; F = F1; cOut = c1; }
        else { sum = s2; ssq = q2; gamma = g2_; beta = b2; W = W2; bias2 = bi2; F = F2; cOut = c2; }
        if (sub < 64)
            fold_frag_elem(sub * 256 + threadIdx.x, sum, ssq, gamma, 1.f / NBATCH, W, F);
        else if (threadIdx.x < 128)
            fold_c_elem(sum, ssq, gamma, beta, 1.f / NBATCH, W, bias2, cOut, sb);
    }
}

// ---------------------------------------------------------------------------
// Fused MFMA branch layer 2: out = relu(Y @ W' + c)
// ---------------------------------------------------------------------------
__device__ void branch_l2_mfma(int tile, const ushort_t* __restrict__ Y,
                               const ushort_t* __restrict__ B,
                               const float* __restrict__ cvec,
                               float* __restrict__ out) {
    int lane = threadIdx.x & 63, wave = threadIdx.x >> 6;
    int m = lane & 15, q = lane >> 4;
    int row0 = tile * 16, n0 = wave * 16;
    f32x4 acc = {0.f, 0.f, 0.f, 0.f};
    const ushort_t* ap = Y + (size_t)(row0 + m) * FDIM + q * 8;
    const ushort_t* bp = B + ((size_t)q * 128 + n0 + m) * 8;
#pragma unroll
    for (int kc = 0; kc < FDIM; kc += 32) {
        bf16x8 av = *(const bf16x8*)(ap + kc);
        bf16x8 bv = *(const bf16x8*)(bp + (size_t)(kc >> 3) * 1024);
        acc = __builtin_amdgcn_mfma_f32_16x16x32_bf16(av, bv, acc, 0, 0, 0);
    }
    int n = n0 + m;
    float c = cvec[n];
#pragma unroll
    for (int r = 0; r < 4; ++r)
        out[(size_t)(row0 + q * 4 + r) * FDIM + n] = fmaxf(acc[r] + c, 0.f);
}

__global__ __launch_bounds__(512) void k_branch_l2_mfma(
        const ushort_t* Ych, const ushort_t* Fch, const float* cch, float* och,
        const ushort_t* Ycl, const ushort_t* Fcl, const float* ccl, float* ocl,
        const ushort_t* Ytg, const ushort_t* Ftg, const float* ctg, float* otg) {
    int b = blockIdx.x;
    if (b < 128)      branch_l2_mfma(b,       Ych, Fch, cch, och);
    else if (b < 256) branch_l2_mfma(b - 128, Ycl, Fcl, ccl, ocl);
    else              branch_l2_mfma(b - 256, Ytg, Ftg, ctg, otg);
}

// ---------------------------------------------------------------------------
extern "C" void kernel_launch(void* const* d_in, const int* in_sizes, int n_in,
                              void* d_out, int out_size, void* d_ws, size_t ws_size,
                              hipStream_t stream) {
    const float* Xs    = (const float*)d_in[0];
    const int*   adj   = (const int*)d_in[1];
    const int*   esrc  = adj;
    const int*   edst  = adj + NEDGES;
    const int*   ibat  = (const int*)d_in[2];
    const float* Xchem = (const float*)d_in[3];
    const float* Xtgt  = (const float*)d_in[4];
    const float* Xcell = (const float*)d_in[5];
    const float* Wc1 = (const float*)d_in[6],  *bc1 = (const float*)d_in[7];
    const float* g1  = (const float*)d_in[8],  *be1 = (const float*)d_in[9];
    const float* Wc2 = (const float*)d_in[10], *bc2 = (const float*)d_in[11];
    const float* g2  = (const float*)d_in[12], *be2 = (const float*)d_in[13];
    const float* Wh1 = (const float*)d_in[14], *bh1 = (const float*)d_in[15];
    const float* gh  = (const float*)d_in[16], *beh = (const float*)d_in[17];
    const float* Wh2 = (const float*)d_in[18], *bh2 = (const float*)d_in[19];
    const float* Wt1 = (const float*)d_in[20], *bt1 = (const float*)d_in[21];
    const float* gt  = (const float*)d_in[22], *bet = (const float*)d_in[23];
    const float* Wt2 = (const float*)d_in[24], *bt2 = (const float*)d_in[25];
    const float* Wg1 = (const float*)d_in[26], *bg1 = (const float*)d_in[27];
    const float* gg  = (const float*)d_in[28], *beg = (const float*)d_in[29];
    const float* Wg2 = (const float*)d_in[30], *bg2 = (const float*)d_in[31];

    // ---- workspace layout ----
    ushort_t* Xs_b = (ushort_t*)d_ws;                        // N*96
    ushort_t* Hbf  = Xs_b + (size_t)NNODES * K1PAD;          // (N+1)*128
    ushort_t* X1b  = Hbf  + ((size_t)NNODES + 1) * FDIM;     // N*128
    ushort_t* X2b  = X1b  + (size_t)NNODES * FDIM;           // N*128
    ushort_t* Fc1  = X2b  + (size_t)NNODES * FDIM;           // 12288
    ushort_t* Fh1  = Fc1 + 12288;                            // 32768
    ushort_t* Ft1  = Fh1 + 32768;                            // 262144
    ushort_t* Fg1  = Ft1 + 262144;                           // 131072
    ushort_t* Fc2  = Fg1 + 131072;                           // 16384
    ushort_t* Fh2  = Fc2 + 16384;
    ushort_t* Ft2  = Fh2 + 16384;
    ushort_t* Fg2  = Ft2 + 16384;
    ushort_t* Ych  = Fg2 + 16384;                            // B*128
    ushort_t* Ytg  = Ych + (size_t)NBATCH * FDIM;
    ushort_t* Ycl  = Ytg + (size_t)NBATCH * FDIM;
    unsigned* deg  = (unsigned*)(Ycl + (size_t)NBATCH * FDIM); // N   (zeroed)
    float*    stats = (float*)(deg + NNODES);                // 5*256 (zeroed, contiguous w/ deg)
    float*    cvec  = stats + 5 * 256;                       // 4*128
    float*    dinv  = cvec + 4 * 128;                        // N
    int*      rowStartP = (int*)(dinv + NNODES);             // N+1
    int*      cursor    = rowStartP + NNODES + 1;            // N
    unsigned* tsum = (unsigned*)(cursor + NNODES);           // SCAN_T
    unsigned* toff = tsum + SCAN_T;                          // SCAN_T
    int*      csrP = (int*)(toff + SCAN_T);                  // CSRP_MAX

    float* sum_g1 = stats + 0 * 256, *ssq_g1 = sum_g1 + 128;
    float* sum_g2 = stats + 1 * 256, *ssq_g2 = sum_g2 + 128;
    float* sum_ch = stats + 2 * 256, *ssq_ch = sum_ch + 128;
    float* sum_tg = stats + 3 * 256, *ssq_tg = sum_tg + 128;
    float* sum_cl = stats + 4 * 256, *ssq_cl = sum_cl + 128;
    float* c_g2 = cvec + 0 * 128;
    float* c_ch = cvec + 1 * 128;
    float* c_tg = cvec + 2 * 128;
    float* c_cl = cvec + 3 * 128;

    float* out_stru = (float*)d_out;
    float* out_chem = out_stru + (size_t)NBATCH * FDIM;
    float* out_tgt  = out_chem + (size_t)NBATCH * FDIM;
    float* out_cell = out_tgt + (size_t)NBATCH * FDIM;

    // 1. zero deg + stats (contiguous)
    hipMemsetAsync(deg, 0, NNODES * sizeof(unsigned) + 5 * 256 * sizeof(float), stream);

    // 2. mega-B: deg | fillcsr | prepXs | prepW1
    k_megaB<<<57962, 256, 0, stream>>>(edst, deg, csrP, Xs, Xs_b,
                                       Wc1, Wh1, Wt1, Wg1, Fc1, Fh1, Ft1, Fg1);

    // 3-5. padded CSR scans
    k_scan1<<<SCAN_T / 256, 256, 0, stream>>>(deg, tsum, dinv);
    k_scan2<<<1, SCAN_T, 0, stream>>>(tsum, toff);
    k_scan3<<<SCAN_T / 256, 256, 0, stream>>>(deg, toff, rowStartP, cursor);

    // 6. mega-A: branch_l1 | scatter x gemm1 interleaved
    k_megaA<<<9759, 512, 0, stream>>>(
        esrc, edst, cursor, csrP, Xs_b, Fc1, dinv, Hbf,
        Xchem, Fh1, bh1, Ych, sum_ch, ssq_ch,
        Xcell, Fg1, bg1, Ycl, sum_cl, ssq_cl,
        Xtgt,  Ft1, bt1, Ytg, sum_tg, ssq_tg);

    // 7. gather 1
    k_gather_fin<<<GB_BLOCKS, 256, 0, stream>>>(Hbf, rowStartP, csrP, dinv,
                                                bc1, X1b, sum_g1, ssq_g1);

    // 8-9. fold BN1 into W2, GEMM 2
    k_fold_g2<<<65, 256, 0, stream>>>(sum_g1, ssq_g1, g1, be1, Wc2, Fc2, c_g2);
    k_gemm2_mfma<<<NNODES / 16, 512, 0, stream>>>(X1b, Fc2, c_g2, dinv, Hbf);

    // 10. gather 2
    k_gather_fin<<<GB_BLOCKS, 256, 0, stream>>>(Hbf, rowStartP, csrP, dinv,
                                                bc2, X2b, sum_g2, ssq_g2);

    // 11. segmax | fold3 fused
    k_segfold<<<1219, 256, 0, stream>>>(
        X2b, ibat, sum_g2, ssq_g2, g2, be2, out_stru,
        sum_ch, ssq_ch, gh, beh, Wh2, bh2, Fh2, c_ch,
        sum_tg, ssq_tg, gt, bet, Wt2, bt2, Ft2, c_tg,
        sum_cl, ssq_cl, gg, beg, Wg2, bg2, Fg2, c_cl);

    // 12. branch layer 2
    k_branch_l2_mfma<<<384, 512, 0, stream>>>(
        Ych, Fh2, c_ch, out_chem,
        Ycl, Fg2, c_cl, out_cell,
        Ytg, Ft2, c_tg, out_tgt);
}